// Round 10
// baseline (202.921 us; speedup 1.0000x reference)
//
#include <hip/hip_runtime.h>
#include <stdint.h>

#define D_MODEL 1024
#define NHEAD 16
#define HEAD_DIM 64
#define SEQ 2048
#define BATCH 2
#define MROWS (BATCH*SEQ)   // 4096
#define KVBLK 128
#define KVTILES (SEQ/KVBLK) // 16

typedef unsigned short u16;
typedef short bf16x8 __attribute__((ext_vector_type(8)));
typedef float f32x4 __attribute__((ext_vector_type(4)));
typedef float f32x16 __attribute__((ext_vector_type(16)));

__device__ inline float bf2f(u16 h){ return __uint_as_float(((unsigned)h)<<16); }
__device__ inline u16 f2bf(float x){
  unsigned u = __float_as_uint(x);
  unsigned r = (u + 0x7FFFu + ((u>>16)&1u)) >> 16;
  return (u16)r;
}

// Builtin MFMA: compiler inserts MFMA hazard nops/waitcnts (R2 lesson).
__device__ inline f32x4 mfma_bf16(bf16x8 a, bf16x8 b, f32x4 c){
  return __builtin_amdgcn_mfma_f32_16x16x32_bf16(a, b, c, 0, 0, 0);
}
__device__ inline f32x16 mfma32_bf16(bf16x8 a, bf16x8 b, f32x16 c){
  return __builtin_amdgcn_mfma_f32_32x32x16_bf16(a, b, c, 0, 0, 0);
}

__device__ inline void gld_lds16(const u16* g, u16* l){
  __builtin_amdgcn_global_load_lds(
      (const __attribute__((address_space(1))) void*)g,
      (__attribute__((address_space(3))) void*)l, 16, 0, 0);
}

// unified LDS swizzle: distinct per row within 8-row AND across 8-row stripes
__device__ inline int swz8(int row){ return (row ^ (row >> 3)) & 7; }

// pack two f32 -> (bf16(p0) | bf16(p1)<<16), round-half-up (P only)
__device__ inline uint32_t pack_bf2(float p0, float p1){
  uint32_t u0 = __float_as_uint(p0) + 0x8000u;
  uint32_t u1 = __float_as_uint(p1) + 0x8000u;
  return __builtin_amdgcn_perm(u1, u0, 0x07060302u);
}

// ---------------- pack kernels ----------------
__global__ __launch_bounds__(256) void pack_split(const float* __restrict__ src,
                                                  u16* __restrict__ hi, u16* __restrict__ lo, int n4){
  int i = blockIdx.x*256 + threadIdx.x;
  if (i >= n4) return;
  float4 v = ((const float4*)src)[i];
  float vv[4] = {v.x, v.y, v.z, v.w};
  u16 h[4], l[4];
  #pragma unroll
  for (int j=0;j<4;j++){
    h[j] = f2bf(vv[j]);
    l[j] = f2bf(vv[j] - bf2f(h[j]));
  }
  ((ushort4*)hi)[i] = make_ushort4(h[0],h[1],h[2],h[3]);
  ((ushort4*)lo)[i] = make_ushort4(l[0],l[1],l[2],l[3]);
}

// all 4 weight matrices in one launch (1024 blocks per tensor)
__global__ __launch_bounds__(256) void pack_w(const float* __restrict__ wq, const float* __restrict__ wk,
                                              const float* __restrict__ wv, const float* __restrict__ wo,
                                              u16* __restrict__ qkv_hi, u16* __restrict__ qkv_lo,
                                              u16* __restrict__ wo_hi, u16* __restrict__ wo_lo){
  int which = blockIdx.x >> 10;
  int i = ((blockIdx.x & 1023) << 8) + threadIdx.x;  // float4 idx 0..262143
  const float* src = which==0 ? wq : which==1 ? wk : which==2 ? wv : wo;
  u16* hi = (which==3) ? wo_hi : qkv_hi + ((size_t)which << 20);
  u16* lo = (which==3) ? wo_lo : qkv_lo + ((size_t)which << 20);
  float4 v = ((const float4*)src)[i];
  float vv[4] = {v.x, v.y, v.z, v.w};
  u16 h[4], l[4];
  #pragma unroll
  for (int j=0;j<4;j++){
    h[j] = f2bf(vv[j]);
    l[j] = f2bf(vv[j] - bf2f(h[j]));
  }
  ((ushort4*)hi)[i] = make_ushort4(h[0],h[1],h[2],h[3]);
  ((ushort4*)lo)[i] = make_ushort4(l[0],l[1],l[2],l[3]);
}

// ---------------- fused QKV GEMM: 256x256, BK=64, 3-barrier pipeline ---------
// Virtual K'=3072 (48 tiles of 64): t<16: x_hi*w_hi; <32: x_lo*w_hi; <48: x_hi*w_lo.
// LDS 2 bufs x 64KB; per buf regions: A_k0@0,A_k1@8192,B_k0@16384,B_k1@24576.
// RACE FIX vs R9: every certify is a {vmcnt(N); s_barrier} PAIR (vmcnt alone
// only covers the wave's OWN loads; the barrier after it makes it collective —
// this is R8's proven pattern). Per tile t (buf=t&1, obuf=buf^1):
//   [invariant: buf slice0 collectively certified]
//   read slice0 frags (12 ds_read); issue G1[t] -> obuf slice1 (t+1)
//   vmcnt(8); s_barrier        -> certify slice1 (G1[t-1])
//   read A1 (8);  MFMA0 (32)   [A1 latency hides under MFMA0]
//   read B1 (4);  MFMA1 (32)
//   s_barrier                  -> WAR: all waves done reading buf
//   issue G2[t] -> buf slice0 (t+2)
//   vmcnt(8); s_barrier        -> certify next tile's slice0 (G2[t-1])
// Ledger (4 gld per G, steady): enter={G1[t-1],G2[t-1]}=8; +G1[t]=12;
// vmcnt(8) drains G1[t-1]; +G2[t]=12; vmcnt(8) drains G2[t-1]. Tail:
// t=NT-2 second wait vmcnt(4); t=NT-1 first wait vmcnt(0), stages skipped.
__global__ __launch_bounds__(512) void gemm_qkv(
    const u16* __restrict__ a_hi, const u16* __restrict__ a_lo,
    const u16* __restrict__ b_hi, const u16* __restrict__ b_lo,
    const float* __restrict__ bq, const float* __restrict__ bk_,
    const float* __restrict__ bv,
    u16* __restrict__ qb, u16* __restrict__ kb, u16* __restrict__ vb,
    const float* __restrict__ gq, const float* __restrict__ gk)
{
  __shared__ u16 lds8[2][32768];
  const int tid = threadIdx.x;          // 0..511
  const int lane = tid & 63;
  const int w = tid >> 6;               // 8 waves
  const int wr = w >> 2, wc = w & 3;    // 2 x 4
  const int l15 = lane & 15;
  const int m0 = blockIdx.x * 256;
  const int n0 = blockIdx.y * 256;
  const int NT = 48;

  f32x4 acc[8][4];
  #pragma unroll
  for (int i=0;i<8;i++)
    #pragma unroll
    for (int j=0;j<4;j++) acc[i][j] = (f32x4){0.f,0.f,0.f,0.f};

  // stage one 256x32 region (2 gld/thread). region: 0=A_k0 1=A_k1 2=B_k0 3=B_k1
  auto stage = [&](int buf, int region, int tt){
    const int pass = tt >> 4;
    const u16* src = (region < 2) ? (pass==1 ? a_lo : a_hi)
                                  : (pass==2 ? b_lo : b_hi);
    const int base0 = (region < 2) ? m0 : n0;
    const int kk = ((tt & 15) << 6) + ((region & 1) << 5);
    u16* dst = &lds8[buf][region << 13];
    #pragma unroll
    for (int r2=0;r2<2;r2++){
      int idx = tid + (r2<<9);                // 0..1023
      int row = idx >> 2, s = idx & 3;
      int g = s ^ ((row >> 1) & 3);           // inverse-swz source (rule #21)
      gld_lds16(src + (size_t)(base0+row)*1024 + kk + (g<<3), dst + (idx<<3));
    }
  };

  const int slot = ((lane >> 4) ^ ((l15 >> 1) & 3)) << 3;  // R7/R8-verified read swz
  const int arow = wr*128 + l15;
  const int brow = wc*64  + l15;

  // ---- prologue: buf0 slice0+slice1, buf1 slice0; certify buf0 slice0 ----
  stage(0,0,0); stage(0,2,0);   // buf0 slice0
  stage(0,1,0); stage(0,3,0);   // buf0 slice1 (G1[-1])
  stage(1,0,1); stage(1,2,1);   // buf1 slice0 (G2[-1])
  asm volatile("s_waitcnt vmcnt(8)" ::: "memory");
  __builtin_amdgcn_s_barrier();   // buf0 slice0 collectively certified

  for (int t=0; t<NT; ++t){
    const int buf = t & 1, obuf = buf ^ 1;
    const u16* A0 = &lds8[buf][0];
    const u16* A1 = &lds8[buf][8192];
    const u16* B0 = &lds8[buf][16384];
    const u16* B1 = &lds8[buf][24576];

    // slice0 frags (certified at loop entry)
    bf16x8 af0[8], bf0[4];
    #pragma unroll
    for (int mf=0;mf<8;mf++) af0[mf] = *(const bf16x8*)&A0[(arow+mf*16)*32 + slot];
    #pragma unroll
    for (int nf=0;nf<4;nf++) bf0[nf] = *(const bf16x8*)&B0[(brow+nf*16)*32 + slot];
    if (t+1 < NT){ stage(obuf, 1, t+1); stage(obuf, 3, t+1); }   // G1[t]

    // certify slice1 (G1[t-1]) — collective pair
    if (t < NT-1) asm volatile("s_waitcnt vmcnt(8)" ::: "memory");
    else          asm volatile("s_waitcnt vmcnt(0)" ::: "memory");
    __builtin_amdgcn_s_barrier();

    bf16x8 af1[8];
    #pragma unroll
    for (int mf=0;mf<8;mf++) af1[mf] = *(const bf16x8*)&A1[(arow+mf*16)*32 + slot];

    __builtin_amdgcn_s_setprio(1);
    #pragma unroll
    for (int mf=0;mf<8;mf++)
      #pragma unroll
      for (int nf=0;nf<4;nf++)
        acc[mf][nf] = mfma_bf16(af0[mf], bf0[nf], acc[mf][nf]);
    __builtin_amdgcn_s_setprio(0);

    bf16x8 bf1[4];
    #pragma unroll
    for (int nf=0;nf<4;nf++) bf1[nf] = *(const bf16x8*)&B1[(brow+nf*16)*32 + slot];

    __builtin_amdgcn_s_setprio(1);
    #pragma unroll
    for (int mf=0;mf<8;mf++)
      #pragma unroll
      for (int nf=0;nf<4;nf++)
        acc[mf][nf] = mfma_bf16(af1[mf], bf1[nf], acc[mf][nf]);
    __builtin_amdgcn_s_setprio(0);

    __builtin_amdgcn_s_barrier();                 // WAR: all reads of buf done
    if (t+2 < NT){
      stage(buf, 0, t+2); stage(buf, 2, t+2);     // G2[t]
      asm volatile("s_waitcnt vmcnt(8)" ::: "memory");
      __builtin_amdgcn_s_barrier();               // certify slice0 of t+1
    } else if (t == NT-2){
      asm volatile("s_waitcnt vmcnt(4)" ::: "memory");
      __builtin_amdgcn_s_barrier();               // certify slice0 of NT-1
    }
  }

  // ---- epilogue: bias -> RMSNorm -> SFN -> q/k/v [B,H,L,64] bf16 (verified) --
  const int gcolbase = n0 + wc*64;
  const int sidx = gcolbase >> 6;   // 0..47 head-segment
  const int ttype = sidx < 16 ? 0 : (sidx < 32 ? 1 : 2);
  u16* dst = ttype==0 ? qb : (ttype==1 ? kb : vb);
  const float* bsrc = ttype==0 ? bq : (ttype==1 ? bk_ : bv);
  const int h = sidx - (ttype==1 ? 16 : (ttype==2 ? 32 : 0));
  float gvals[4], bvals[4];
  #pragma unroll
  for (int j=0;j<4;j++){
    int dh = j*16 + l15;
    bvals[j] = bsrc[(gcolbase & 1023) + dh];
    gvals[j] = ttype==0 ? gq[dh] : (ttype==1 ? gk[dh] : 1.0f);
  }
  #pragma unroll
  for (int mf=0;mf<8;mf++){
    #pragma unroll
    for (int r=0;r<4;r++){
      float tv[4];
      float ssq = 0.f;
      #pragma unroll
      for (int j=0;j<4;j++){ tv[j] = acc[mf][j][r] + bvals[j]; ssq += tv[j]*tv[j]; }
      ssq += __shfl_xor(ssq, 1);
      ssq += __shfl_xor(ssq, 2);
      ssq += __shfl_xor(ssq, 4);
      ssq += __shfl_xor(ssq, 8);
      float s = 1.0f;
      if (ttype < 2) s = 1.0f / sqrtf(ssq * (1.0f/64.0f) + 1e-6f);
      int row = m0 + wr*128 + mf*16 + (lane>>4)*4 + r;
      int bi = row >> 11, li = row & 2047;
      size_t obase = ((size_t)(bi*NHEAD + h)*SEQ + li)*HEAD_DIM;
      #pragma unroll
      for (int j=0;j<4;j++){
        float val = tv[j] * s * gvals[j];
        float z = rintf(val * 2.0f);           // round-half-even == jnp.round
        z = fminf(8.0f, fmaxf(-8.0f, z));
        dst[obase + j*16 + l15] = f2bf(z * 0.5f);   // exact in bf16
      }
    }
  }
}

// ---------------- GEMM: C = A * B^T (+bias) fp32 out (out-projection) --------
__global__ __launch_bounds__(256) void gemm_bt(
    const u16* __restrict__ a_hi, const u16* __restrict__ b_hi,
    const float* __restrict__ bias, float* __restrict__ out_f,
    int M, int N, int K)
{
  __shared__ u16 lds[2][8192];
  const int tid = threadIdx.x;
  const int lane = tid & 63;
  const int w = tid >> 6;
  const int wr = w >> 1, wc = w & 1;
  const int m0 = blockIdx.x * 128;
  const int n0 = blockIdx.y * 128;
  const int NT = K / 32;

  f32x4 acc[4][4];
  #pragma unroll
  for (int i=0;i<4;i++)
    #pragma unroll
    for (int j=0;j<4;j++) acc[i][j] = (f32x4){0.f,0.f,0.f,0.f};

  auto stage = [&](int buf, int kt){
    int kk = kt * 32;
    u16* base = &lds[buf][0];
    #pragma unroll
    for (int r=0;r<2;r++){
      const u16* g = a_hi + (size_t)(m0 + (tid>>2) + r*64)*K + kk + (tid&3)*8;
      gld_lds16(g, base + w*512 + r*2048);
    }
    #pragma unroll
    for (int r=0;r<2;r++){
      const u16* g = b_hi + (size_t)(n0 + (tid>>2) + r*64)*K + kk + (tid&3)*8;
      gld_lds16(g, base + 4096 + w*512 + r*2048);
    }
  };

  stage(0, 0);
  for (int kt=0; kt<NT; ++kt){
    __syncthreads();
    if (kt+1 < NT) stage((kt+1)&1, kt+1);
    const u16* la = &lds[kt&1][0];
    const u16* lb = &lds[kt&1][4096];
    const int koff = (lane>>4)*8;
    const int rowa = wr*64 + (lane&15);
    const int rowb = wc*64 + (lane&15);
    bf16x8 af[4], bfv[4];
    #pragma unroll
    for (int i=0;i<4;i++) af[i]  = *(const bf16x8*)&la[(rowa + i*16)*32 + koff];
    #pragma unroll
    for (int i=0;i<4;i++) bfv[i] = *(const bf16x8*)&lb[(rowb + i*16)*32 + koff];
    #pragma unroll
    for (int i=0;i<4;i++)
      #pragma unroll
      for (int j=0;j<4;j++)
        acc[i][j] = mfma_bf16(af[i], bfv[j], acc[i][j]);
  }

  const int gcolbase = n0 + wc*64;
  #pragma unroll
  for (int j=0;j<4;j++){
    float bj = bias[gcolbase + j*16 + (lane&15)];
    #pragma unroll
    for (int i=0;i<4;i++){
      int row = m0 + wr*64 + i*16 + (lane>>4)*4;
      #pragma unroll
      for (int r=0;r<4;r++)
        out_f[(size_t)(row+r)*N + gcolbase + j*16 + (lane&15)] = acc[i][j][r] + bj;
    }
  }
}

// ---------------- v [B,H,L,64] -> vT [B,H,64,L] ----------------
__global__ __launch_bounds__(256) void transpose_v(const u16* __restrict__ v, u16* __restrict__ vt){
  __shared__ u16 tl[64][66];
  int bh = blockIdx.x >> 5;
  int l0 = (blockIdx.x & 31) * 64;
  int tid = threadIdx.x;
  #pragma unroll
  for (int it=0; it<2; ++it){
    int idx = tid + it*256;
    int row = idx >> 3, g = idx & 7;
    bf16x8 d = *(const bf16x8*)(v + ((size_t)bh*SEQ + l0 + row)*64 + g*8);
    #pragma unroll
    for (int j=0;j<8;j++) tl[row][g*8+j] = (u16)d[j];
  }
  __syncthreads();
  #pragma unroll
  for (int it=0; it<2; ++it){
    int idx = tid + it*256;
    int dh = idx >> 3, g = idx & 7;
    u16 tmp[8];
    #pragma unroll
    for (int j=0;j<8;j++) tmp[j] = tl[g*8+j][dh];
    *(bf16x8*)(vt + ((size_t)bh*HEAD_DIM + dh)*SEQ + l0 + g*8) = *(const bf16x8*)tmp;
  }
}

// ---------------- flash attention (v6: KVBLK=128, 2x64 halves) --------------
__global__ __launch_bounds__(256) void attn_kernel(
    const u16* __restrict__ qb, const u16* __restrict__ kb, const u16* __restrict__ vt,
    u16* __restrict__ attn_out)
{
  __shared__ u16 lds_k[2][KVBLK*64];   // [kv][d], swizzled (16KB each)
  __shared__ u16 lds_v[2][64*KVBLK];   // [dh][kv], swizzled (16KB each)
  const int tid = threadIdx.x, lane = tid & 63, w = tid >> 6;
  const int bh = blockIdx.y;
  const int q0 = blockIdx.x * 128;
  const size_t kvbase = (size_t)bh * SEQ * HEAD_DIM;
  const size_t vtbase = (size_t)bh * HEAD_DIM * SEQ;
  const int l31 = lane & 31, hi = lane >> 5;

  // Q frags (B operand): Q[q0+w*32+l31][kd*16 + hi*8 + j], scale 0.125 exact
  bf16x8 qf[4];
  #pragma unroll
  for (int kd=0; kd<4; kd++){
    const u16* g = qb + kvbase + (size_t)(q0 + w*32 + l31)*64 + kd*16 + hi*8;
    bf16x8 v = *(const bf16x8*)g;
    #pragma unroll
    for (int j=0;j<8;j++) ((u16*)&v)[j] = f2bf(bf2f((u16)v[j]) * 0.125f);
    qf[kd] = v;
  }

  float m_s = -3.0e38f, l_s = 0.f;
  f32x16 o0, o1;
  #pragma unroll
  for (int r=0;r<16;r++){ o0[r] = 0.f; o1[r] = 0.f; }

  auto stage = [&](int buf, int t){
    const int kv0 = t * KVBLK;
    #pragma unroll
    for (int r=0;r<4;r++){
      int idx = tid + r*256;
      int row = idx >> 3, grp = idx & 7;          // K: [128 kv][8 grp]
      const u16* g = kb + kvbase + (size_t)(kv0 + row)*64 + ((grp ^ swz8(row))<<3);
      gld_lds16(g, &lds_k[buf][idx<<3]);
    }
    #pragma unroll
    for (int r=0;r<4;r++){
      int idx = tid + r*256;
      int row = idx >> 4, grp = idx & 15;         // V: [64 dh][16 grp]
      const u16* g = vt + vtbase + (size_t)row*SEQ + kv0 + ((grp ^ swz8(row))<<3);
      gld_lds16(g, &lds_v[buf][idx<<3]);
    }
  };

  stage(0, 0);
  for (int t=0; t<KVTILES; ++t){
    __syncthreads();                        // tile t staged; buf t^1 free
    if (t+1 < KVTILES) stage((t+1)&1, t+1); // overlap with compute(t)
    const int buf = t & 1;

    #pragma unroll
    for (int half=0; half<2; ++half){
      // ---- S^T = K Q ----
      f32x16 s0, s1;
      #pragma unroll
      for (int r=0;r<16;r++){ s0[r] = 0.f; s1[r] = 0.f; }
      const int row0 = half*64 + l31;
      const int row1 = half*64 + 32 + l31;
      __builtin_amdgcn_s_setprio(1);
      #pragma unroll
      for (int kd=0; kd<4; kd++){
        bf16x8 a0 = *(const bf16x8*)&lds_k[buf][row0*64 + (((kd*2+hi) ^ swz8(row0))<<3)];
        bf16x8 a1 = *(const bf16x8*)&lds_k[buf][row1*64 + (((kd*2+hi) ^ swz8(row1))<<3)];
        s0 = mfma32_bf16(a0, qf[kd], s0);
        s1 = mfma32_bf16(a1, qf[kd], s1);
      }
      __builtin_amdgcn_s_setprio(0);

      // ---- softmax for lane's q-row: 31 in-reg fmax + 1 shfl ----
      float pmax = s0[0];
      #pragma unroll
      for (int r=1;r<16;r++) pmax = fmaxf(pmax, s0[r]);
      #pragma unroll
      for (int r=0;r<16;r++) pmax = fmaxf(pmax, s1[r]);
      pmax = fmaxf(pmax, __shfl_xor(pmax, 32));

      if (__any(pmax - m_s > 8.0f)) {       // defer-max rescale (T13)
        float mnew = fmaxf(m_s, pmax);
        float c = __expf(m_s - mnew);
        m_s = mnew;
        l_s *= c;
        #pragma unroll
        for (int r=0;r<16;r++){
          float cr = __shfl(c, (r&3) + 8*(r>>2) + 4*hi);
          o0[r] *= cr; o1[r] *= cr;
        }
      }

      float rsum = 0.f;
      #pragma unroll
      for (int r=0;r<16;r++){ float p = __expf(s0[r] - m_s); s0[r] = p; rsum += p; }
      #pragma unroll
      for (int r=0;r<16;r++){ float p = __expf(s1[r] - m_s); s1[r] = p; rsum += p; }
      rsum += __shfl_xor(rsum, 32);
      l_s += rsum;

      // ---- P -> bf16 packed words ----
      uint32_t W[2][4][2];
      #pragma unroll
      for (int g=0; g<4; g++){
        W[0][g][0] = pack_bf2(s0[g*4+0], s0[g*4+1]);
        W[0][g][1] = pack_bf2(s0[g*4+2], s0[g*4+3]);
        W[1][g][0] = pack_bf2(s1[g*4+0], s1[g*4+1]);
        W[1][g][1] = pack_bf2(s1[g*4+2], s1[g*4+3]);
      }
      // ---- assemble PV A-frags in-register (T12) ----
      bf16x8 pa[4];
      #pragma unroll
      for (int ks=0; ks<4; ks++){
        const int kvb = ks >> 1, ks0 = ks & 1;
        uint32_t own0 = hi ? W[kvb][ks0*2+1][0] : W[kvb][ks0*2][0];
        uint32_t own1 = hi ? W[kvb][ks0*2+1][1] : W[kvb][ks0*2][1];
        uint32_t t0   = hi ? W[kvb][ks0*2][0]   : W[kvb][ks0*2+1][0];
        uint32_t t1   = hi ? W[kvb][ks0*2][1]   : W[kvb][ks0*2+1][1];
        uint32_t sw0  = (uint32_t)__shfl_xor((int)t0, 32);
        uint32_t sw1  = (uint32_t)__shfl_xor((int)t1, 32);
        uint32_t words[4];
        words[0] = hi ? sw0 : own0;
        words[1] = hi ? sw1 : own1;
        words[2] = hi ? own0 : sw0;
        words[3] = hi ? own1 : sw1;
        pa[ks] = *(const bf16x8*)words;
      }

      // ---- O += P V ----
      __builtin_amdgcn_s_setprio(1);
      #pragma unroll
      for (int ks=0; ks<4; ks++){
        const int rv0 = l31, rv1 = 32 + l31;
        const int cg = half*8 + ks*2 + hi;
        bf16x8 vb0 = *(const bf16x8*)&lds_v[buf][rv0*KVBLK + ((cg ^ swz8(rv0))<<3)];
        bf16x8 vb1 = *(const bf16x8*)&lds_v[buf][rv1*KVBLK + ((cg ^ swz8(rv1))<<3)];
        o0 = mfma32_bf16(pa[ks], vb0, o0);
        o1 = mfma32_bf16(pa[ks], vb1, o1);
      }
      __builtin_amdgcn_s_setprio(0);
    }
  }

  // ---- epilogue ----
  const int b = bh >> 4, h = bh & 15;
  #pragma unroll
  for (int r=0;r<16;r++){
    int q = (r&3) + 8*(r>>2) + 4*hi;
    float linv = 1.0f / __shfl(l_s, q);
    int row = q0 + w*32 + q;
    size_t obase = ((size_t)b*SEQ + row)*D_MODEL + h*64;
    attn_out[obase + l31]      = f2bf(o0[r] * linv);
    attn_out[obase + 32 + l31] = f2bf(o1[r] * linv);
  }
}

// ---------------- host ----------------
extern "C" void kernel_launch(void* const* d_in, const int* in_sizes, int n_in,
                              void* d_out, int out_size, void* d_ws, size_t ws_size,
                              hipStream_t stream){
  const float* x  = (const float*)d_in[0];
  const float* wq = (const float*)d_in[1];
  const float* bq = (const float*)d_in[2];
  const float* wk = (const float*)d_in[3];
  const float* bk = (const float*)d_in[4];
  const float* wv = (const float*)d_in[5];
  const float* bv = (const float*)d_in[6];
  const float* wo = (const float*)d_in[7];
  const float* bo = (const float*)d_in[8];
  const float* gq = (const float*)d_in[9];
  const float* gk = (const float*)d_in[10];
  float* out = (float*)d_out;

  char* ws = (char*)d_ws;
  size_t off = 0;
  auto alloc = [&](size_t bytes) -> char* {
    char* p = ws + off; off += (bytes + 255) & ~(size_t)255; return p;
  };
  const size_t ND = (size_t)MROWS * D_MODEL;       // 4M
  u16* x_hi    = (u16*)alloc(ND*2);
  u16* x_lo    = (u16*)alloc(ND*2);
  u16* wqkv_hi = (u16*)alloc((size_t)3072*1024*2);
  u16* wqkv_lo = (u16*)alloc((size_t)3072*1024*2);
  u16* wo_hi   = (u16*)alloc((size_t)1024*1024*2);
  u16* wo_lo   = (u16*)alloc((size_t)1024*1024*2);
  u16* q_bf    = (u16*)alloc(ND*2);
  u16* k_bf    = (u16*)alloc(ND*2);
  u16* v_bf    = (u16*)alloc(ND*2);
  u16* vT      = (u16*)alloc(ND*2);
  u16* attn_bf = (u16*)alloc(ND*2);
  (void)ws_size; (void)in_sizes; (void)n_in; (void)out_size;

  pack_split<<<4096, 256, 0, stream>>>(x, x_hi, x_lo, (int)(ND/4));
  pack_w<<<4096, 256, 0, stream>>>(wq, wk, wv, wo, wqkv_hi, wqkv_lo, wo_hi, wo_lo);

  gemm_qkv<<<dim3(16,12), 512, 0, stream>>>(x_hi, x_lo, wqkv_hi, wqkv_lo,
        bq, bk, bv, q_bf, k_bf, v_bf, gq, gk);

  transpose_v<<<1024, 256, 0, stream>>>(v_bf, vT);

  attn_kernel<<<dim3(16,32), 256, 0, stream>>>(q_bf, k_bf, vT, attn_bf);

  gemm_bt<<<dim3(32,8), 256, 0, stream>>>(attn_bf, wo_hi, bo, out, MROWS, 1024, 1024);
}

// Round 12
// 172.802 us; speedup vs baseline: 1.1743x; 1.1743x over previous
//
#include <hip/hip_runtime.h>
#include <stdint.h>

#define D_MODEL 1024
#define NHEAD 16
#define HEAD_DIM 64
#define SEQ 2048
#define BATCH 2
#define MROWS (BATCH*SEQ)   // 4096
#define KVBLK 128
#define KVTILES (SEQ/KVBLK) // 16

typedef unsigned short u16;
typedef short bf16x8 __attribute__((ext_vector_type(8)));
typedef float f32x4 __attribute__((ext_vector_type(4)));
typedef float f32x16 __attribute__((ext_vector_type(16)));

__device__ inline float bf2f(u16 h){ return __uint_as_float(((unsigned)h)<<16); }
__device__ inline u16 f2bf(float x){
  unsigned u = __float_as_uint(x);
  unsigned r = (u + 0x7FFFu + ((u>>16)&1u)) >> 16;
  return (u16)r;
}

// Builtin MFMA: compiler inserts MFMA hazard nops/waitcnts (R2 lesson).
__device__ inline f32x4 mfma_bf16(bf16x8 a, bf16x8 b, f32x4 c){
  return __builtin_amdgcn_mfma_f32_16x16x32_bf16(a, b, c, 0, 0, 0);
}
__device__ inline f32x16 mfma32_bf16(bf16x8 a, bf16x8 b, f32x16 c){
  return __builtin_amdgcn_mfma_f32_32x32x16_bf16(a, b, c, 0, 0, 0);
}

__device__ inline void gld_lds16(const u16* g, u16* l){
  __builtin_amdgcn_global_load_lds(
      (const __attribute__((address_space(1))) void*)g,
      (__attribute__((address_space(3))) void*)l, 16, 0, 0);
}

// unified LDS swizzle: distinct per row within 8-row AND across 8-row stripes
__device__ inline int swz8(int row){ return (row ^ (row >> 3)) & 7; }

// pack two f32 -> (bf16(p0) | bf16(p1)<<16), round-half-up (P only)
__device__ inline uint32_t pack_bf2(float p0, float p1){
  uint32_t u0 = __float_as_uint(p0) + 0x8000u;
  uint32_t u1 = __float_as_uint(p1) + 0x8000u;
  return __builtin_amdgcn_perm(u1, u0, 0x07060302u);
}

// ---------------- single pack kernel (x split + all weights) ----------------
// blocks 0..4095: x -> bf16 hi/lo split (1M float4)
// blocks 4096..8191: which=(b-4096)>>10: wq/wk/wv -> bf16 hi/lo; wo -> bf16 hi.
__global__ __launch_bounds__(256) void pack_all(
    const float* __restrict__ x,
    const float* __restrict__ wq, const float* __restrict__ wk,
    const float* __restrict__ wv, const float* __restrict__ wo,
    u16* __restrict__ x_hi, u16* __restrict__ x_lo,
    u16* __restrict__ qkv_hi, u16* __restrict__ qkv_lo,
    u16* __restrict__ wo_hi)
{
  int b = blockIdx.x;
  const float* src;
  u16 *hi, *lo;
  int i;
  if (b < 4096){
    src = x; i = b*256 + threadIdx.x;
    hi = x_hi; lo = x_lo;
  } else {
    int which = (b - 4096) >> 10;
    i = ((b - 4096) & 1023)*256 + threadIdx.x;
    src = which==0 ? wq : which==1 ? wk : which==2 ? wv : wo;
    if (which == 3){ hi = wo_hi; lo = nullptr; }
    else { hi = qkv_hi + ((size_t)which << 20); lo = qkv_lo + ((size_t)which << 20); }
  }
  float4 v = ((const float4*)src)[i];
  float vv[4] = {v.x, v.y, v.z, v.w};
  u16 h[4], l[4];
  #pragma unroll
  for (int j=0;j<4;j++){
    h[j] = f2bf(vv[j]);
    l[j] = f2bf(vv[j] - bf2f(h[j]));
  }
  ((ushort4*)hi)[i] = make_ushort4(h[0],h[1],h[2],h[3]);
  if (lo) ((ushort4*)lo)[i] = make_ushort4(l[0],l[1],l[2],l[3]);
}

// ---------------- fused QKV GEMM (R6-proven: bf16 3-pass, 128x128, 48KB) -----
// acc = x_hi*w_hi^T + x_lo*w_hi^T + x_hi*w_lo^T, phase-fused:
//   steps 0..31:  stage {A_hi, A_lo, B_hi} (24KB/buf) -> 32 MFMA/barrier
//   steps 32..63: stage {A_hi, B_lo}                  -> 16 MFMA/barrier
// LDS 48KB (3 blocks/CU). Epilogue: bias -> RMSNorm(gq/gk) -> SFN -> q/k/v bf16.
__global__ __launch_bounds__(256) void gemm_qkv(
    const u16* __restrict__ a_hi, const u16* __restrict__ a_lo,
    const u16* __restrict__ b_hi, const u16* __restrict__ b_lo,
    const float* __restrict__ bq, const float* __restrict__ bk_,
    const float* __restrict__ bv,
    u16* __restrict__ qb, u16* __restrict__ kb, u16* __restrict__ vb,
    const float* __restrict__ gq, const float* __restrict__ gk)
{
  __shared__ u16 lds[2][12288];   // [0):A_hi [4096):A_lo [8192):B
  const int tid = threadIdx.x;
  const int lane = tid & 63;
  const int w = tid >> 6;
  const int wr = w >> 1, wc = w & 1;
  const int m0 = blockIdx.x * 128;
  const int n0 = blockIdx.y * 128;
  const int K = 1024;

  f32x4 acc[4][4];
  #pragma unroll
  for (int i=0;i<4;i++)
    #pragma unroll
    for (int j=0;j<4;j++) acc[i][j] = (f32x4){0.f,0.f,0.f,0.f};

  auto stage = [&](int buf, int kt){
    u16* base = &lds[buf][0];
    if (kt < 32){
      int kk = kt << 5;
      #pragma unroll
      for (int r=0;r<2;r++){
        const u16* g = a_hi + (size_t)(m0 + (tid>>2) + r*64)*K + kk + (tid&3)*8;
        gld_lds16(g, base + w*512 + r*2048);
      }
      #pragma unroll
      for (int r=0;r<2;r++){
        const u16* g = a_lo + (size_t)(m0 + (tid>>2) + r*64)*K + kk + (tid&3)*8;
        gld_lds16(g, base + 4096 + w*512 + r*2048);
      }
      #pragma unroll
      for (int r=0;r<2;r++){
        const u16* g = b_hi + (size_t)(n0 + (tid>>2) + r*64)*K + kk + (tid&3)*8;
        gld_lds16(g, base + 8192 + w*512 + r*2048);
      }
    } else {
      int kk = (kt-32) << 5;
      #pragma unroll
      for (int r=0;r<2;r++){
        const u16* g = a_hi + (size_t)(m0 + (tid>>2) + r*64)*K + kk + (tid&3)*8;
        gld_lds16(g, base + w*512 + r*2048);
      }
      #pragma unroll
      for (int r=0;r<2;r++){
        const u16* g = b_lo + (size_t)(n0 + (tid>>2) + r*64)*K + kk + (tid&3)*8;
        gld_lds16(g, base + 8192 + w*512 + r*2048);
      }
    }
  };

  const int koff = (lane>>4)*8;
  const int rowa = wr*64 + (lane&15);
  const int rowb = wc*64 + (lane&15);

  stage(0, 0);
  for (int kt=0; kt<64; ++kt){
    __syncthreads();
    if (kt+1 < 64) stage((kt+1)&1, kt+1);
    const u16* la = &lds[kt&1][0];
    const u16* lb = &lds[kt&1][8192];
    bf16x8 bfv[4];
    #pragma unroll
    for (int j=0;j<4;j++) bfv[j] = *(const bf16x8*)&lb[(rowb + j*16)*32 + koff];
    bf16x8 af[4];
    #pragma unroll
    for (int i=0;i<4;i++) af[i] = *(const bf16x8*)&la[(rowa + i*16)*32 + koff];
    #pragma unroll
    for (int i=0;i<4;i++)
      #pragma unroll
      for (int j=0;j<4;j++)
        acc[i][j] = mfma_bf16(af[i], bfv[j], acc[i][j]);
    if (kt < 32){
      const u16* ll = &lds[kt&1][4096];
      bf16x8 al[4];
      #pragma unroll
      for (int i=0;i<4;i++) al[i] = *(const bf16x8*)&ll[(rowa + i*16)*32 + koff];
      #pragma unroll
      for (int i=0;i<4;i++)
        #pragma unroll
        for (int j=0;j<4;j++)
          acc[i][j] = mfma_bf16(al[i], bfv[j], acc[i][j]);
    }
  }

  // ---- epilogue: bias -> RMSNorm -> SFN -> q/k/v [B,H,L,64] bf16 ----
  const int gcolbase = n0 + wc*64;
  const int sidx = gcolbase >> 6;   // 0..47 head-segment
  const int ttype = sidx < 16 ? 0 : (sidx < 32 ? 1 : 2);
  u16* dst = ttype==0 ? qb : (ttype==1 ? kb : vb);
  const float* bsrc = ttype==0 ? bq : (ttype==1 ? bk_ : bv);
  const int h = sidx - (ttype==1 ? 16 : (ttype==2 ? 32 : 0));
  float gvals[4], bvals[4];
  #pragma unroll
  for (int j=0;j<4;j++){
    int dh = j*16 + (lane&15);
    bvals[j] = bsrc[((gcolbase & 1023) + dh) & 1023];
    gvals[j] = ttype==0 ? gq[dh] : (ttype==1 ? gk[dh] : 1.0f);
  }
  #pragma unroll
  for (int i=0;i<4;i++){
    #pragma unroll
    for (int r=0;r<4;r++){
      float tv[4];
      float ssq = 0.f;
      #pragma unroll
      for (int j=0;j<4;j++){ tv[j] = acc[i][j][r] + bvals[j]; ssq += tv[j]*tv[j]; }
      ssq += __shfl_xor(ssq, 1);
      ssq += __shfl_xor(ssq, 2);
      ssq += __shfl_xor(ssq, 4);
      ssq += __shfl_xor(ssq, 8);
      float s = 1.0f;
      if (ttype < 2) s = 1.0f / sqrtf(ssq * (1.0f/64.0f) + 1e-6f);
      int row = m0 + wr*64 + i*16 + (lane>>4)*4 + r;
      int bi = row >> 11, li = row & 2047;
      size_t obase = ((size_t)(bi*NHEAD + h)*SEQ + li)*HEAD_DIM;
      #pragma unroll
      for (int j=0;j<4;j++){
        float val = tv[j] * s * gvals[j];
        float z = rintf(val * 2.0f);           // round-half-even == jnp.round
        z = fminf(8.0f, fmaxf(-8.0f, z));
        dst[obase + j*16 + (lane&15)] = f2bf(z * 0.5f);   // exact in bf16
      }
    }
  }
}

// ---------------- GEMM: C = A * B^T (+bias) fp32 out (out-projection) --------
__global__ __launch_bounds__(256) void gemm_bt(
    const u16* __restrict__ a_hi, const u16* __restrict__ b_hi,
    const float* __restrict__ bias, float* __restrict__ out_f,
    int M, int N, int K)
{
  __shared__ u16 lds[2][8192];
  const int tid = threadIdx.x;
  const int lane = tid & 63;
  const int w = tid >> 6;
  const int wr = w >> 1, wc = w & 1;
  const int m0 = blockIdx.x * 128;
  const int n0 = blockIdx.y * 128;
  const int NT = K / 32;

  f32x4 acc[4][4];
  #pragma unroll
  for (int i=0;i<4;i++)
    #pragma unroll
    for (int j=0;j<4;j++) acc[i][j] = (f32x4){0.f,0.f,0.f,0.f};

  auto stage = [&](int buf, int kt){
    int kk = kt * 32;
    u16* base = &lds[buf][0];
    #pragma unroll
    for (int r=0;r<2;r++){
      const u16* g = a_hi + (size_t)(m0 + (tid>>2) + r*64)*K + kk + (tid&3)*8;
      gld_lds16(g, base + w*512 + r*2048);
    }
    #pragma unroll
    for (int r=0;r<2;r++){
      const u16* g = b_hi + (size_t)(n0 + (tid>>2) + r*64)*K + kk + (tid&3)*8;
      gld_lds16(g, base + 4096 + w*512 + r*2048);
    }
  };

  stage(0, 0);
  for (int kt=0; kt<NT; ++kt){
    __syncthreads();
    if (kt+1 < NT) stage((kt+1)&1, kt+1);
    const u16* la = &lds[kt&1][0];
    const u16* lb = &lds[kt&1][4096];
    const int koff = (lane>>4)*8;
    const int rowa = wr*64 + (lane&15);
    const int rowb = wc*64 + (lane&15);
    bf16x8 af[4], bfv[4];
    #pragma unroll
    for (int i=0;i<4;i++) af[i]  = *(const bf16x8*)&la[(rowa + i*16)*32 + koff];
    #pragma unroll
    for (int i=0;i<4;i++) bfv[i] = *(const bf16x8*)&lb[(rowb + i*16)*32 + koff];
    #pragma unroll
    for (int i=0;i<4;i++)
      #pragma unroll
      for (int j=0;j<4;j++)
        acc[i][j] = mfma_bf16(af[i], bfv[j], acc[i][j]);
  }

  const int gcolbase = n0 + wc*64;
  #pragma unroll
  for (int j=0;j<4;j++){
    float bj = bias[gcolbase + j*16 + (lane&15)];
    #pragma unroll
    for (int i=0;i<4;i++){
      int row = m0 + wr*64 + i*16 + (lane>>4)*4;
      #pragma unroll
      for (int r=0;r<4;r++)
        out_f[(size_t)(row+r)*N + gcolbase + j*16 + (lane&15)] = acc[i][j][r] + bj;
    }
  }
}

// ---------------- v [B,H,L,64] -> vT [B,H,64,L] ----------------
__global__ __launch_bounds__(256) void transpose_v(const u16* __restrict__ v, u16* __restrict__ vt){
  __shared__ u16 tl[64][66];
  int bh = blockIdx.x >> 5;
  int l0 = (blockIdx.x & 31) * 64;
  int tid = threadIdx.x;
  #pragma unroll
  for (int it=0; it<2; ++it){
    int idx = tid + it*256;
    int row = idx >> 3, g = idx & 7;
    bf16x8 d = *(const bf16x8*)(v + ((size_t)bh*SEQ + l0 + row)*64 + g*8);
    #pragma unroll
    for (int j=0;j<8;j++) tl[row][g*8+j] = (u16)d[j];
  }
  __syncthreads();
  #pragma unroll
  for (int it=0; it<2; ++it){
    int idx = tid + it*256;
    int dh = idx >> 3, g = idx & 7;
    u16 tmp[8];
    #pragma unroll
    for (int j=0;j<8;j++) tmp[j] = tl[g*8+j][dh];
    *(bf16x8*)(vt + ((size_t)bh*HEAD_DIM + dh)*SEQ + l0 + g*8) = *(const bf16x8*)tmp;
  }
}

// ---------------- flash attention (v7: bounded-score softmax, no max-track) --
// q,k are SFN outputs: ||q||2 <= 10, ||k||2 <= 10 => |s| <= 0.125*100 = 12.5.
// exp(s) <= 2.7e5; l <= 5.5e8; o <= 2.2e9 — all fp32-safe, and the constant
// shift cancels exactly in o/l (softmax shift-invariance). So no running max,
// no rescale, no defer-max branch.
__global__ __launch_bounds__(256) void attn_kernel(
    const u16* __restrict__ qb, const u16* __restrict__ kb, const u16* __restrict__ vt,
    u16* __restrict__ attn_out)
{
  __shared__ u16 lds_k[2][KVBLK*64];   // [kv][d], swizzled (16KB each)
  __shared__ u16 lds_v[2][64*KVBLK];   // [dh][kv], swizzled (16KB each)
  const int tid = threadIdx.x, lane = tid & 63, w = tid >> 6;
  const int bh = blockIdx.y;
  const int q0 = blockIdx.x * 128;
  const size_t kvbase = (size_t)bh * SEQ * HEAD_DIM;
  const size_t vtbase = (size_t)bh * HEAD_DIM * SEQ;
  const int l31 = lane & 31, hi = lane >> 5;

  // Q frags (B operand): Q[q0+w*32+l31][kd*16 + hi*8 + j], scale 0.125 exact
  bf16x8 qf[4];
  #pragma unroll
  for (int kd=0; kd<4; kd++){
    const u16* g = qb + kvbase + (size_t)(q0 + w*32 + l31)*64 + kd*16 + hi*8;
    bf16x8 v = *(const bf16x8*)g;
    #pragma unroll
    for (int j=0;j<8;j++) ((u16*)&v)[j] = f2bf(bf2f((u16)v[j]) * 0.125f);
    qf[kd] = v;
  }

  float l_s = 0.f;
  f32x16 o0, o1;
  #pragma unroll
  for (int r=0;r<16;r++){ o0[r] = 0.f; o1[r] = 0.f; }

  auto stage = [&](int buf, int t){
    const int kv0 = t * KVBLK;
    #pragma unroll
    for (int r=0;r<4;r++){
      int idx = tid + r*256;
      int row = idx >> 3, grp = idx & 7;          // K: [128 kv][8 grp]
      const u16* g = kb + kvbase + (size_t)(kv0 + row)*64 + ((grp ^ swz8(row))<<3);
      gld_lds16(g, &lds_k[buf][idx<<3]);
    }
    #pragma unroll
    for (int r=0;r<4;r++){
      int idx = tid + r*256;
      int row = idx >> 4, grp = idx & 15;         // V: [64 dh][16 grp]
      const u16* g = vt + vtbase + (size_t)row*SEQ + kv0 + ((grp ^ swz8(row))<<3);
      gld_lds16(g, &lds_v[buf][idx<<3]);
    }
  };

  stage(0, 0);
  for (int t=0; t<KVTILES; ++t){
    __syncthreads();                        // tile t staged; buf t^1 free
    if (t+1 < KVTILES) stage((t+1)&1, t+1); // overlap with compute(t)
    const int buf = t & 1;

    #pragma unroll
    for (int half=0; half<2; ++half){
      // ---- S^T = K Q ----
      f32x16 s0, s1;
      #pragma unroll
      for (int r=0;r<16;r++){ s0[r] = 0.f; s1[r] = 0.f; }
      const int row0 = half*64 + l31;
      const int row1 = half*64 + 32 + l31;
      __builtin_amdgcn_s_setprio(1);
      #pragma unroll
      for (int kd=0; kd<4; kd++){
        bf16x8 a0 = *(const bf16x8*)&lds_k[buf][row0*64 + (((kd*2+hi) ^ swz8(row0))<<3)];
        bf16x8 a1 = *(const bf16x8*)&lds_k[buf][row1*64 + (((kd*2+hi) ^ swz8(row1))<<3)];
        s0 = mfma32_bf16(a0, qf[kd], s0);
        s1 = mfma32_bf16(a1, qf[kd], s1);
      }
      __builtin_amdgcn_s_setprio(0);

      // ---- softmax numerator: P = exp(s) (bounded, no max-subtraction) ----
      float rsum = 0.f;
      #pragma unroll
      for (int r=0;r<16;r++){ float p = __expf(s0[r]); s0[r] = p; rsum += p; }
      #pragma unroll
      for (int r=0;r<16;r++){ float p = __expf(s1[r]); s1[r] = p; rsum += p; }
      rsum += __shfl_xor(rsum, 32);
      l_s += rsum;

      // ---- P -> bf16 packed words ----
      uint32_t W[2][4][2];
      #pragma unroll
      for (int g=0; g<4; g++){
        W[0][g][0] = pack_bf2(s0[g*4+0], s0[g*4+1]);
        W[0][g][1] = pack_bf2(s0[g*4+2], s0[g*4+3]);
        W[1][g][0] = pack_bf2(s1[g*4+0], s1[g*4+1]);
        W[1][g][1] = pack_bf2(s1[g*4+2], s1[g*4+3]);
      }
      // ---- assemble PV A-frags in-register (T12) ----
      bf16x8 pa[4];
      #pragma unroll
      for (int ks=0; ks<4; ks++){
        const int kvb = ks >> 1, ks0 = ks & 1;
        uint32_t own0 = hi ? W[kvb][ks0*2+1][0] : W[kvb][ks0*2][0];
        uint32_t own1 = hi ? W[kvb][ks0*2+1][1] : W[kvb][ks0*2][1];
        uint32_t t0   = hi ? W[kvb][ks0*2][0]   : W[kvb][ks0*2+1][0];
        uint32_t t1   = hi ? W[kvb][ks0*2][1]   : W[kvb][ks0*2+1][1];
        uint32_t sw0  = (uint32_t)__shfl_xor((int)t0, 32);
        uint32_t sw1  = (uint32_t)__shfl_xor((int)t1, 32);
        uint32_t words[4];
        words[0] = hi ? sw0 : own0;
        words[1] = hi ? sw1 : own1;
        words[2] = hi ? own0 : sw0;
        words[3] = hi ? own1 : sw1;
        pa[ks] = *(const bf16x8*)words;
      }

      // ---- O += P V ----
      __builtin_amdgcn_s_setprio(1);
      #pragma unroll
      for (int ks=0; ks<4; ks++){
        const int rv0 = l31, rv1 = 32 + l31;
        const int cg = half*8 + ks*2 + hi;
        bf16x8 vb0 = *(const bf16x8*)&lds_v[buf][rv0*KVBLK + ((cg ^ swz8(rv0))<<3)];
        bf16x8 vb1 = *(const bf16x8*)&lds_v[buf][rv1*KVBLK + ((cg ^ swz8(rv1))<<3)];
        o0 = mfma32_bf16(pa[ks], vb0, o0);
        o1 = mfma32_bf16(pa[ks], vb1, o1);
      }
      __builtin_amdgcn_s_setprio(0);
    }
  }

  // ---- epilogue ----
  const int b = bh >> 4, h = bh & 15;
  #pragma unroll
  for (int r=0;r<16;r++){
    int q = (r&3) + 8*(r>>2) + 4*hi;
    float linv = 1.0f / __shfl(l_s, q);
    int row = q0 + w*32 + q;
    size_t obase = ((size_t)b*SEQ + row)*D_MODEL + h*64;
    attn_out[obase + l31]      = f2bf(o0[r] * linv);
    attn_out[obase + 32 + l31] = f2bf(o1[r] * linv);
  }
}

// ---------------- host ----------------
extern "C" void kernel_launch(void* const* d_in, const int* in_sizes, int n_in,
                              void* d_out, int out_size, void* d_ws, size_t ws_size,
                              hipStream_t stream){
  const float* x  = (const float*)d_in[0];
  const float* wq = (const float*)d_in[1];
  const float* bq = (const float*)d_in[2];
  const float* wk = (const float*)d_in[3];
  const float* bk = (const float*)d_in[4];
  const float* wv = (const float*)d_in[5];
  const float* bv = (const float*)d_in[6];
  const float* wo = (const float*)d_in[7];
  const float* bo = (const float*)d_in[8];
  const float* gq = (const float*)d_in[9];
  const float* gk = (const float*)d_in[10];
  float* out = (float*)d_out;

  char* ws = (char*)d_ws;
  size_t off = 0;
  auto alloc = [&](size_t bytes) -> char* {
    char* p = ws + off; off += (bytes + 255) & ~(size_t)255; return p;
  };
  const size_t ND = (size_t)MROWS * D_MODEL;       // 4M
  u16* x_hi    = (u16*)alloc(ND*2);
  u16* x_lo    = (u16*)alloc(ND*2);
  u16* wqkv_hi = (u16*)alloc((size_t)3072*1024*2);
  u16* wqkv_lo = (u16*)alloc((size_t)3072*1024*2);
  u16* wo_hi   = (u16*)alloc((size_t)1024*1024*2);
  u16* q_bf    = (u16*)alloc(ND*2);
  u16* k_bf    = (u16*)alloc(ND*2);
  u16* v_bf    = (u16*)alloc(ND*2);
  u16* vT      = (u16*)alloc(ND*2);
  u16* attn_bf = (u16*)alloc(ND*2);
  (void)ws_size; (void)in_sizes; (void)n_in; (void)out_size;

  pack_all<<<8192, 256, 0, stream>>>(x, wq, wk, wv, wo,
        x_hi, x_lo, wqkv_hi, wqkv_lo, wo_hi);

  gemm_qkv<<<dim3(32,24), 256, 0, stream>>>(x_hi, x_lo, wqkv_hi, wqkv_lo,
        bq, bk, bv, q_bf, k_bf, v_bf, gq, gk);

  transpose_v<<<1024, 256, 0, stream>>>(v_bf, vT);

  attn_kernel<<<dim3(16,32), 256, 0, stream>>>(q_bf, k_bf, vT, attn_bf);

  gemm_bt<<<dim3(32,8), 256, 0, stream>>>(attn_bf, wo_hi, bo, out, MROWS, 1024, 1024);
}

// Round 14
// 170.854 us; speedup vs baseline: 1.1877x; 1.0114x over previous
//
#include <hip/hip_runtime.h>
#include <stdint.h>

#define D_MODEL 1024
#define NHEAD 16
#define HEAD_DIM 64
#define SEQ 2048
#define BATCH 2
#define MROWS (BATCH*SEQ)   // 4096
#define KVBLK 128
#define KVTILES (SEQ/KVBLK) // 16

typedef unsigned short u16;
typedef short bf16x8 __attribute__((ext_vector_type(8)));
typedef _Float16 f16x8 __attribute__((ext_vector_type(8)));
typedef float f32x4 __attribute__((ext_vector_type(4)));
typedef float f32x16 __attribute__((ext_vector_type(16)));

__device__ inline float bf2f(u16 h){ return __uint_as_float(((unsigned)h)<<16); }
__device__ inline u16 f2bf(float x){
  unsigned u = __float_as_uint(x);
  unsigned r = (u + 0x7FFFu + ((u>>16)&1u)) >> 16;
  return (u16)r;
}
__device__ inline u16 f2h(float x){ _Float16 h = (_Float16)x; return *(u16*)&h; }
__device__ inline float h2f(u16 b){ _Float16 h = *(_Float16*)&b; return (float)h; }

// Builtin MFMA: compiler inserts MFMA hazard nops/waitcnts (R2 lesson).
__device__ inline f32x4 mfma_f16(f16x8 a, f16x8 b, f32x4 c){
  return __builtin_amdgcn_mfma_f32_16x16x32_f16(a, b, c, 0, 0, 0);
}
__device__ inline f32x16 mfma32_bf16(bf16x8 a, bf16x8 b, f32x16 c){
  return __builtin_amdgcn_mfma_f32_32x32x16_bf16(a, b, c, 0, 0, 0);
}

__device__ inline void gld_lds16(const u16* g, u16* l){
  __builtin_amdgcn_global_load_lds(
      (const __attribute__((address_space(1))) void*)g,
      (__attribute__((address_space(3))) void*)l, 16, 0, 0);
}

// unified LDS swizzle: distinct per row within 8-row AND across 8-row stripes
__device__ inline int swz8(int row){ return (row ^ (row >> 3)) & 7; }

// pack two f32 -> (bf16(p0) | bf16(p1)<<16), round-half-up (P only)
__device__ inline uint32_t pack_bf2(float p0, float p1){
  uint32_t u0 = __float_as_uint(p0) + 0x8000u;
  uint32_t u1 = __float_as_uint(p1) + 0x8000u;
  return __builtin_amdgcn_perm(u1, u0, 0x07060302u);
}

// ---------------- single pack kernel ----------------
// blocks 0..4095: x -> fp16 hi/lo split (residual ~2^-22 rel)
// blocks 4096..8191: which=(b-4096)>>10: wq/wk/wv -> fp16 hi+lo; wo -> fp16 hi.
__global__ __launch_bounds__(256) void pack_all(
    const float* __restrict__ x,
    const float* __restrict__ wq, const float* __restrict__ wk,
    const float* __restrict__ wv, const float* __restrict__ wo,
    u16* __restrict__ x_hi, u16* __restrict__ x_lo,
    u16* __restrict__ qkv_h, u16* __restrict__ qkv_lo,
    u16* __restrict__ wo_h)
{
  int b = blockIdx.x;
  if (b < 4096){
    int i = b*256 + threadIdx.x;
    float4 v = ((const float4*)x)[i];
    float vv[4] = {v.x, v.y, v.z, v.w};
    u16 h[4], l[4];
    #pragma unroll
    for (int j=0;j<4;j++){
      h[j] = f2h(vv[j]);
      l[j] = f2h(vv[j] - h2f(h[j]));
    }
    ((ushort4*)x_hi)[i] = make_ushort4(h[0],h[1],h[2],h[3]);
    ((ushort4*)x_lo)[i] = make_ushort4(l[0],l[1],l[2],l[3]);
  } else {
    int which = (b - 4096) >> 10;
    int i = ((b - 4096) & 1023)*256 + threadIdx.x;
    const float* src = which==0 ? wq : which==1 ? wk : which==2 ? wv : wo;
    float4 v = ((const float4*)src)[i];
    float vv[4] = {v.x, v.y, v.z, v.w};
    u16 h[4];
    #pragma unroll
    for (int j=0;j<4;j++) h[j] = f2h(vv[j]);
    if (which == 3){
      ((ushort4*)wo_h)[i] = make_ushort4(h[0],h[1],h[2],h[3]);
    } else {
      u16 l[4];
      #pragma unroll
      for (int j=0;j<4;j++) l[j] = f2h(vv[j] - h2f(h[j]));
      ((ushort4*)(qkv_h  + ((size_t)which << 20)))[i] = make_ushort4(h[0],h[1],h[2],h[3]);
      ((ushort4*)(qkv_lo + ((size_t)which << 20)))[i] = make_ushort4(l[0],l[1],l[2],l[3]);
    }
  }
}

// ---------------- fused QKV GEMM (R6/R12-proven skeleton, fp16 3-pass) -------
// t = x_hi*w_h + x_lo*w_h + x_hi*w_lo  (drops only x_lo*w_lo ~2e-7 — exact
// for SFN purposes; this is the R6/R12 numeric structure in fp16).
//   steps 0..31:  stage {A_hi, A_lo, B_h} (24KB/buf) -> 32 MFMA/barrier
//   steps 32..63: stage {A_hi, B_lo}                 -> 16 MFMA/barrier
// LDS 48KB dbuf (3 blocks/CU). Epilogue:
//   Q/K -> bias, RMSNorm(g), SFN -> qb/kb bf16 [B,H,L,64]
//   V   -> bias, SFN -> vT bf16 [B,H,64,L] DIRECTLY (transpose fused, R13-validated)
__global__ __launch_bounds__(256) void gemm_qkv(
    const u16* __restrict__ a_hi, const u16* __restrict__ a_lo,
    const u16* __restrict__ b_h,  const u16* __restrict__ b_lo,
    const float* __restrict__ bq, const float* __restrict__ bk_,
    const float* __restrict__ bv,
    u16* __restrict__ qb, u16* __restrict__ kb, u16* __restrict__ vt,
    const float* __restrict__ gq, const float* __restrict__ gk)
{
  __shared__ u16 lds[2][12288];   // [0):A_hi [4096):A_lo [8192):B
  const int tid = threadIdx.x;
  const int lane = tid & 63;
  const int w = tid >> 6;
  const int wr = w >> 1, wc = w & 1;
  const int l15 = lane & 15, lq = lane >> 4;
  const int m0 = blockIdx.x * 128;
  const int n0 = blockIdx.y * 128;
  const int K = 1024;

  f32x4 acc[4][4];
  #pragma unroll
  for (int i=0;i<4;i++)
    #pragma unroll
    for (int j=0;j<4;j++) acc[i][j] = (f32x4){0.f,0.f,0.f,0.f};

  auto stage = [&](int buf, int kt){
    u16* base = &lds[buf][0];
    if (kt < 32){
      int kk = kt << 5;
      #pragma unroll
      for (int r=0;r<2;r++){
        const u16* g = a_hi + (size_t)(m0 + (tid>>2) + r*64)*K + kk + (tid&3)*8;
        gld_lds16(g, base + w*512 + r*2048);
      }
      #pragma unroll
      for (int r=0;r<2;r++){
        const u16* g = a_lo + (size_t)(m0 + (tid>>2) + r*64)*K + kk + (tid&3)*8;
        gld_lds16(g, base + 4096 + w*512 + r*2048);
      }
      #pragma unroll
      for (int r=0;r<2;r++){
        const u16* g = b_h + (size_t)(n0 + (tid>>2) + r*64)*K + kk + (tid&3)*8;
        gld_lds16(g, base + 8192 + w*512 + r*2048);
      }
    } else {
      int kk = (kt-32) << 5;
      #pragma unroll
      for (int r=0;r<2;r++){
        const u16* g = a_hi + (size_t)(m0 + (tid>>2) + r*64)*K + kk + (tid&3)*8;
        gld_lds16(g, base + w*512 + r*2048);
      }
      #pragma unroll
      for (int r=0;r<2;r++){
        const u16* g = b_lo + (size_t)(n0 + (tid>>2) + r*64)*K + kk + (tid&3)*8;
        gld_lds16(g, base + 8192 + w*512 + r*2048);
      }
    }
  };

  const int koff = lq*8;
  const int rowa = wr*64 + l15;
  const int rowb = wc*64 + l15;

  stage(0, 0);
  for (int kt=0; kt<64; ++kt){
    __syncthreads();
    if (kt+1 < 64) stage((kt+1)&1, kt+1);
    const u16* la = &lds[kt&1][0];
    const u16* lb = &lds[kt&1][8192];
    f16x8 bfv[4];
    #pragma unroll
    for (int j=0;j<4;j++) bfv[j] = *(const f16x8*)&lb[(rowb + j*16)*32 + koff];
    f16x8 af[4];
    #pragma unroll
    for (int i=0;i<4;i++) af[i] = *(const f16x8*)&la[(rowa + i*16)*32 + koff];
    #pragma unroll
    for (int i=0;i<4;i++)
      #pragma unroll
      for (int j=0;j<4;j++)
        acc[i][j] = mfma_f16(af[i], bfv[j], acc[i][j]);
    if (kt < 32){
      const u16* ll = &lds[kt&1][4096];
      f16x8 al[4];
      #pragma unroll
      for (int i=0;i<4;i++) al[i] = *(const f16x8*)&ll[(rowa + i*16)*32 + koff];
      #pragma unroll
      for (int i=0;i<4;i++)
        #pragma unroll
        for (int j=0;j<4;j++)
          acc[i][j] = mfma_f16(al[i], bfv[j], acc[i][j]);
    }
  }

  const int gcolbase = n0 + wc*64;
  const int sidx = gcolbase >> 6;   // 0..47 head-segment
  const int ttype = sidx < 16 ? 0 : (sidx < 32 ? 1 : 2);

  if (ttype < 2){
    // ---- Q/K: bias -> RMSNorm(g) -> SFN -> qb/kb [B,H,L,64] bf16 ----
    u16* dst = ttype==0 ? qb : kb;
    const float* bsrc = ttype==0 ? bq : bk_;
    const int h = sidx - (ttype==1 ? 16 : 0);
    float gvals[4], bvals[4];
    #pragma unroll
    for (int j=0;j<4;j++){
      int dh = j*16 + l15;
      bvals[j] = bsrc[(gcolbase & 1023) + dh];
      gvals[j] = ttype==0 ? gq[dh] : gk[dh];
    }
    #pragma unroll
    for (int i=0;i<4;i++){
      #pragma unroll
      for (int r=0;r<4;r++){
        float tv[4];
        float ssq = 0.f;
        #pragma unroll
        for (int j=0;j<4;j++){ tv[j] = acc[i][j][r] + bvals[j]; ssq += tv[j]*tv[j]; }
        ssq += __shfl_xor(ssq, 1);
        ssq += __shfl_xor(ssq, 2);
        ssq += __shfl_xor(ssq, 4);
        ssq += __shfl_xor(ssq, 8);
        float s = 1.0f / sqrtf(ssq * (1.0f/64.0f) + 1e-6f);
        int row = m0 + wr*64 + i*16 + lq*4 + r;
        int bi = row >> 11, li = row & 2047;
        size_t obase = ((size_t)(bi*NHEAD + h)*SEQ + li)*HEAD_DIM;
        #pragma unroll
        for (int j=0;j<4;j++){
          float val = tv[j] * s * gvals[j];
          float z = rintf(val * 2.0f);           // round-half-even == jnp.round
          z = fminf(8.0f, fmaxf(-8.0f, z));
          dst[obase + j*16 + l15] = f2bf(z * 0.5f);   // exact in bf16
        }
      }
    }
  } else {
    // ---- V: bias -> SFN -> vT [B,H,64,L] bf16 directly (transpose fused) ----
    const int h = sidx - 32;
    float bvals[4];
    #pragma unroll
    for (int j=0;j<4;j++) bvals[j] = bv[(gcolbase - 2048) + j*16 + l15];
    #pragma unroll
    for (int i=0;i<4;i++){
      int row0 = m0 + wr*64 + i*16 + lq*4;   // 4 consecutive rows
      int bi = row0 >> 11, li0 = row0 & 2047;
      #pragma unroll
      for (int j=0;j<4;j++){
        u16 h4[4];
        #pragma unroll
        for (int r=0;r<4;r++){
          float val = acc[i][j][r] + bvals[j];
          float z = rintf(val * 2.0f);
          z = fminf(8.0f, fmaxf(-8.0f, z));
          h4[r] = f2bf(z * 0.5f);
        }
        int dh = j*16 + l15;
        *(ushort4*)&vt[(((size_t)(bi*NHEAD + h))*HEAD_DIM + dh)*SEQ + li0] =
            make_ushort4(h4[0],h4[1],h4[2],h4[3]);
      }
    }
  }
}

// ---------------- GEMM: out = attn * wo^T + bias (fp16 operands, fp32 out) ---
__global__ __launch_bounds__(256) void gemm_bt(
    const u16* __restrict__ a_h, const u16* __restrict__ b_h,
    const float* __restrict__ bias, float* __restrict__ out_f,
    int M, int N, int K)
{
  __shared__ u16 lds[2][8192];
  const int tid = threadIdx.x;
  const int lane = tid & 63;
  const int w = tid >> 6;
  const int wr = w >> 1, wc = w & 1;
  const int m0 = blockIdx.x * 128;
  const int n0 = blockIdx.y * 128;
  const int NT = K / 32;

  f32x4 acc[4][4];
  #pragma unroll
  for (int i=0;i<4;i++)
    #pragma unroll
    for (int j=0;j<4;j++) acc[i][j] = (f32x4){0.f,0.f,0.f,0.f};

  auto stage = [&](int buf, int kt){
    int kk = kt * 32;
    u16* base = &lds[buf][0];
    #pragma unroll
    for (int r=0;r<2;r++){
      const u16* g = a_h + (size_t)(m0 + (tid>>2) + r*64)*K + kk + (tid&3)*8;
      gld_lds16(g, base + w*512 + r*2048);
    }
    #pragma unroll
    for (int r=0;r<2;r++){
      const u16* g = b_h + (size_t)(n0 + (tid>>2) + r*64)*K + kk + (tid&3)*8;
      gld_lds16(g, base + 4096 + w*512 + r*2048);
    }
  };

  stage(0, 0);
  for (int kt=0; kt<NT; ++kt){
    __syncthreads();
    if (kt+1 < NT) stage((kt+1)&1, kt+1);
    const u16* la = &lds[kt&1][0];
    const u16* lb = &lds[kt&1][4096];
    const int koff = (lane>>4)*8;
    const int rowa = wr*64 + (lane&15);
    const int rowb = wc*64 + (lane&15);
    f16x8 af[4], bfv[4];
    #pragma unroll
    for (int i=0;i<4;i++) af[i]  = *(const f16x8*)&la[(rowa + i*16)*32 + koff];
    #pragma unroll
    for (int i=0;i<4;i++) bfv[i] = *(const f16x8*)&lb[(rowb + i*16)*32 + koff];
    #pragma unroll
    for (int i=0;i<4;i++)
      #pragma unroll
      for (int j=0;j<4;j++)
        acc[i][j] = mfma_f16(af[i], bfv[j], acc[i][j]);
  }

  const int gcolbase = n0 + wc*64;
  #pragma unroll
  for (int j=0;j<4;j++){
    float bj = bias[gcolbase + j*16 + (lane&15)];
    #pragma unroll
    for (int i=0;i<4;i++){
      int row = m0 + wr*64 + i*16 + (lane>>4)*4;
      #pragma unroll
      for (int r=0;r<4;r++)
        out_f[(size_t)(row+r)*N + gcolbase + j*16 + (lane&15)] = acc[i][j][r] + bj;
    }
  }
}

// ---------------- flash attention (v7 + fp16 output) ------------------------
// Bounded scores (|s|<=12.5) -> no max-tracking (shift-invariance exact).
// P stays bf16 (range up to e^12.5 ~ 2.7e5 exceeds fp16 max). Output fp16.
__global__ __launch_bounds__(256) void attn_kernel(
    const u16* __restrict__ qb, const u16* __restrict__ kb, const u16* __restrict__ vt,
    u16* __restrict__ attn_out)
{
  __shared__ u16 lds_k[2][KVBLK*64];   // [kv][d], swizzled (16KB each)
  __shared__ u16 lds_v[2][64*KVBLK];   // [dh][kv], swizzled (16KB each)
  const int tid = threadIdx.x, lane = tid & 63, w = tid >> 6;
  const int bh = blockIdx.y;
  const int q0 = blockIdx.x * 128;
  const size_t kvbase = (size_t)bh * SEQ * HEAD_DIM;
  const size_t vtbase = (size_t)bh * HEAD_DIM * SEQ;
  const int l31 = lane & 31, hi = lane >> 5;

  // Q frags (B operand): Q[q0+w*32+l31][kd*16 + hi*8 + j], scale 0.125 exact
  bf16x8 qf[4];
  #pragma unroll
  for (int kd=0; kd<4; kd++){
    const u16* g = qb + kvbase + (size_t)(q0 + w*32 + l31)*64 + kd*16 + hi*8;
    bf16x8 v = *(const bf16x8*)g;
    #pragma unroll
    for (int j=0;j<8;j++) ((u16*)&v)[j] = f2bf(bf2f((u16)v[j]) * 0.125f);
    qf[kd] = v;
  }

  float l_s = 0.f;
  f32x16 o0, o1;
  #pragma unroll
  for (int r=0;r<16;r++){ o0[r] = 0.f; o1[r] = 0.f; }

  auto stage = [&](int buf, int t){
    const int kv0 = t * KVBLK;
    #pragma unroll
    for (int r=0;r<4;r++){
      int idx = tid + r*256;
      int row = idx >> 3, grp = idx & 7;          // K: [128 kv][8 grp]
      const u16* g = kb + kvbase + (size_t)(kv0 + row)*64 + ((grp ^ swz8(row))<<3);
      gld_lds16(g, &lds_k[buf][idx<<3]);
    }
    #pragma unroll
    for (int r=0;r<4;r++){
      int idx = tid + r*256;
      int row = idx >> 4, grp = idx & 15;         // V: [64 dh][16 grp]
      const u16* g = vt + vtbase + (size_t)row*SEQ + kv0 + ((grp ^ swz8(row))<<3);
      gld_lds16(g, &lds_v[buf][idx<<3]);
    }
  };

  stage(0, 0);
  for (int t=0; t<KVTILES; ++t){
    __syncthreads();                        // tile t staged; buf t^1 free
    if (t+1 < KVTILES) stage((t+1)&1, t+1); // overlap with compute(t)
    const int buf = t & 1;

    #pragma unroll
    for (int half=0; half<2; ++half){
      // ---- S^T = K Q ----
      f32x16 s0, s1;
      #pragma unroll
      for (int r=0;r<16;r++){ s0[r] = 0.f; s1[r] = 0.f; }
      const int row0 = half*64 + l31;
      const int row1 = half*64 + 32 + l31;
      __builtin_amdgcn_s_setprio(1);
      #pragma unroll
      for (int kd=0; kd<4; kd++){
        bf16x8 a0 = *(const bf16x8*)&lds_k[buf][row0*64 + (((kd*2+hi) ^ swz8(row0))<<3)];
        bf16x8 a1 = *(const bf16x8*)&lds_k[buf][row1*64 + (((kd*2+hi) ^ swz8(row1))<<3)];
        s0 = mfma32_bf16(a0, qf[kd], s0);
        s1 = mfma32_bf16(a1, qf[kd], s1);
      }
      __builtin_amdgcn_s_setprio(0);

      // ---- softmax numerator: P = exp(s) (bounded, no max-subtraction) ----
      float rsum = 0.f;
      #pragma unroll
      for (int r=0;r<16;r++){ float p = __expf(s0[r]); s0[r] = p; rsum += p; }
      #pragma unroll
      for (int r=0;r<16;r++){ float p = __expf(s1[r]); s1[r] = p; rsum += p; }
      rsum += __shfl_xor(rsum, 32);
      l_s += rsum;

      // ---- P -> bf16 packed words ----
      uint32_t W[2][4][2];
      #pragma unroll
      for (int g=0; g<4; g++){
        W[0][g][0] = pack_bf2(s0[g*4+0], s0[g*4+1]);
        W[0][g][1] = pack_bf2(s0[g*4+2], s0[g*4+3]);
        W[1][g][0] = pack_bf2(s1[g*4+0], s1[g*4+1]);
        W[1][g][1] = pack_bf2(s1[g*4+2], s1[g*4+3]);
      }
      // ---- assemble PV A-frags in-register (T12) ----
      bf16x8 pa[4];
      #pragma unroll
      for (int ks=0; ks<4; ks++){
        const int kvb = ks >> 1, ks0 = ks & 1;
        uint32_t own0 = hi ? W[kvb][ks0*2+1][0] : W[kvb][ks0*2][0];
        uint32_t own1 = hi ? W[kvb][ks0*2+1][1] : W[kvb][ks0*2][1];
        uint32_t t0   = hi ? W[kvb][ks0*2][0]   : W[kvb][ks0*2+1][0];
        uint32_t t1   = hi ? W[kvb][ks0*2][1]   : W[kvb][ks0*2+1][1];
        uint32_t sw0  = (uint32_t)__shfl_xor((int)t0, 32);
        uint32_t sw1  = (uint32_t)__shfl_xor((int)t1, 32);
        uint32_t words[4];
        words[0] = hi ? sw0 : own0;
        words[1] = hi ? sw1 : own1;
        words[2] = hi ? own0 : sw0;
        words[3] = hi ? own1 : sw1;
        pa[ks] = *(const bf16x8*)words;
      }

      // ---- O += P V ----
      __builtin_amdgcn_s_setprio(1);
      #pragma unroll
      for (int ks=0; ks<4; ks++){
        const int rv0 = l31, rv1 = 32 + l31;
        const int cg = half*8 + ks*2 + hi;
        bf16x8 vb0 = *(const bf16x8*)&lds_v[buf][rv0*KVBLK + ((cg ^ swz8(rv0))<<3)];
        bf16x8 vb1 = *(const bf16x8*)&lds_v[buf][rv1*KVBLK + ((cg ^ swz8(rv1))<<3)];
        o0 = mfma32_bf16(pa[ks], vb0, o0);
        o1 = mfma32_bf16(pa[ks], vb1, o1);
      }
      __builtin_amdgcn_s_setprio(0);
    }
  }

  // ---- epilogue: fp16 output ----
  const int b = bh >> 4, h = bh & 15;
  #pragma unroll
  for (int r=0;r<16;r++){
    int q = (r&3) + 8*(r>>2) + 4*hi;
    float linv = 1.0f / __shfl(l_s, q);
    int row = q0 + w*32 + q;
    size_t obase = ((size_t)b*SEQ + row)*D_MODEL + h*64;
    attn_out[obase + l31]      = f2h(o0[r] * linv);
    attn_out[obase + 32 + l31] = f2h(o1[r] * linv);
  }
}

// ---------------- host ----------------
extern "C" void kernel_launch(void* const* d_in, const int* in_sizes, int n_in,
                              void* d_out, int out_size, void* d_ws, size_t ws_size,
                              hipStream_t stream){
  const float* x  = (const float*)d_in[0];
  const float* wq = (const float*)d_in[1];
  const float* bq = (const float*)d_in[2];
  const float* wk = (const float*)d_in[3];
  const float* bk = (const float*)d_in[4];
  const float* wv = (const float*)d_in[5];
  const float* bv = (const float*)d_in[6];
  const float* wo = (const float*)d_in[7];
  const float* bo = (const float*)d_in[8];
  const float* gq = (const float*)d_in[9];
  const float* gk = (const float*)d_in[10];
  float* out = (float*)d_out;

  char* ws = (char*)d_ws;
  size_t off = 0;
  auto alloc = [&](size_t bytes) -> char* {
    char* p = ws + off; off += (bytes + 255) & ~(size_t)255; return p;
  };
  const size_t ND = (size_t)MROWS * D_MODEL;       // 4M
  u16* x_hi    = (u16*)alloc(ND*2);                // fp16
  u16* x_lo    = (u16*)alloc(ND*2);                // fp16
  u16* wqkv_h  = (u16*)alloc((size_t)3072*1024*2); // fp16 (wq|wk|wv hi)
  u16* wqkv_lo = (u16*)alloc((size_t)3072*1024*2); // fp16 (wq|wk|wv lo)
  u16* wo_h    = (u16*)alloc((size_t)1024*1024*2); // fp16
  u16* q_bf    = (u16*)alloc(ND*2);
  u16* k_bf    = (u16*)alloc(ND*2);
  u16* vT      = (u16*)alloc(ND*2);
  u16* attn_h  = (u16*)alloc(ND*2);                // fp16
  (void)ws_size; (void)in_sizes; (void)n_in; (void)out_size;

  pack_all<<<8192, 256, 0, stream>>>(x, wq, wk, wv, wo,
        x_hi, x_lo, wqkv_h, wqkv_lo, wo_h);

  gemm_qkv<<<dim3(32,24), 256, 0, stream>>>(x_hi, x_lo, wqkv_h, wqkv_lo,
        bq, bk, bv, q_bf, k_bf, vT, gq, gk);

  attn_kernel<<<dim3(16,32), 256, 0, stream>>>(q_bf, k_bf, vT, attn_h);

  gemm_bt<<<dim3(32,8), 256, 0, stream>>>(attn_h, wo_h, bo, out, MROWS, 1024, 1024);
}

// Round 17
// 167.960 us; speedup vs baseline: 1.2082x; 1.0172x over previous
//
#include <hip/hip_runtime.h>
#include <stdint.h>

#define D_MODEL 1024
#define NHEAD 16
#define HEAD_DIM 64
#define SEQ 2048
#define BATCH 2
#define MROWS (BATCH*SEQ)   // 4096
#define KVBLK 128
#define KVTILES (SEQ/KVBLK) // 16

typedef unsigned short u16;
typedef short bf16x8 __attribute__((ext_vector_type(8)));
typedef _Float16 f16x8 __attribute__((ext_vector_type(8)));
typedef __fp16 hf2 __attribute__((ext_vector_type(2)));
typedef float f32x4 __attribute__((ext_vector_type(4)));
typedef float f32x16 __attribute__((ext_vector_type(16)));

__device__ inline float bf2f(u16 h){ return __uint_as_float(((unsigned)h)<<16); }
__device__ inline u16 f2bf(float x){
  unsigned u = __float_as_uint(x);
  unsigned r = (u + 0x7FFFu + ((u>>16)&1u)) >> 16;
  return (u16)r;
}
__device__ inline u16 f2h(float x){ _Float16 h = (_Float16)x; return *(u16*)&h; }
__device__ inline float h2f(u16 b){ _Float16 h = *(_Float16*)&b; return (float)h; }

// Builtin MFMA: compiler inserts MFMA hazard nops/waitcnts (R2 lesson).
__device__ inline f32x4 mfma_f16(f16x8 a, f16x8 b, f32x4 c){
  return __builtin_amdgcn_mfma_f32_16x16x32_f16(a, b, c, 0, 0, 0);
}
__device__ inline f32x16 mfma32_bf16(bf16x8 a, bf16x8 b, f32x16 c){
  return __builtin_amdgcn_mfma_f32_32x32x16_bf16(a, b, c, 0, 0, 0);
}
__device__ inline f32x16 mfma32_f16(f16x8 a, f16x8 b, f32x16 c){
  return __builtin_amdgcn_mfma_f32_32x32x16_f16(a, b, c, 0, 0, 0);
}

__device__ inline void gld_lds16(const u16* g, u16* l){
  __builtin_amdgcn_global_load_lds(
      (const __attribute__((address_space(1))) void*)g,
      (__attribute__((address_space(3))) void*)l, 16, 0, 0);
}

// unified LDS swizzle: distinct per row within 8-row AND across 8-row stripes
__device__ inline int swz8(int row){ return (row ^ (row >> 3)) & 7; }

// pack two f32 -> fp16x2 word (RTZ, 1 instruction) — P only
__device__ inline uint32_t pack_h2(float p0, float p1){
  hf2 t = __builtin_amdgcn_cvt_pkrtz(p0, p1);
  uint32_t r;
  __builtin_memcpy(&r, &t, 4);
  return r;
}

// ---------------- single pack kernel ----------------
// blocks 0..4095: x -> fp16 hi/lo split (residual ~2^-22 rel)
// blocks 4096..8191: wq/wk/wv -> fp16 hi+lo; wo -> fp16 hi.
__global__ __launch_bounds__(256) void pack_all(
    const float* __restrict__ x,
    const float* __restrict__ wq, const float* __restrict__ wk,
    const float* __restrict__ wv, const float* __restrict__ wo,
    u16* __restrict__ x_hi, u16* __restrict__ x_lo,
    u16* __restrict__ qkv_h, u16* __restrict__ qkv_lo,
    u16* __restrict__ wo_h)
{
  int b = blockIdx.x;
  if (b < 4096){
    int i = b*256 + threadIdx.x;
    float4 v = ((const float4*)x)[i];
    float vv[4] = {v.x, v.y, v.z, v.w};
    u16 h[4], l[4];
    #pragma unroll
    for (int j=0;j<4;j++){
      h[j] = f2h(vv[j]);
      l[j] = f2h(vv[j] - h2f(h[j]));
    }
    ((ushort4*)x_hi)[i] = make_ushort4(h[0],h[1],h[2],h[3]);
    ((ushort4*)x_lo)[i] = make_ushort4(l[0],l[1],l[2],l[3]);
  } else {
    int which = (b - 4096) >> 10;
    int i = ((b - 4096) & 1023)*256 + threadIdx.x;
    const float* src = which==0 ? wq : which==1 ? wk : which==2 ? wv : wo;
    float4 v = ((const float4*)src)[i];
    float vv[4] = {v.x, v.y, v.z, v.w};
    u16 h[4];
    #pragma unroll
    for (int j=0;j<4;j++) h[j] = f2h(vv[j]);
    if (which == 3){
      ((ushort4*)wo_h)[i] = make_ushort4(h[0],h[1],h[2],h[3]);
    } else {
      u16 l[4];
      #pragma unroll
      for (int j=0;j<4;j++) l[j] = f2h(vv[j] - h2f(h[j]));
      ((ushort4*)(qkv_h  + ((size_t)which << 20)))[i] = make_ushort4(h[0],h[1],h[2],h[3]);
      ((ushort4*)(qkv_lo + ((size_t)which << 20)))[i] = make_ushort4(l[0],l[1],l[2],l[3]);
    }
  }
}

// ---------------- fused QKV GEMM (R14-proven: fp16 3-pass for ALL of QKV) ----
// t = x_hi*w_h + x_lo*w_h + x_hi*w_lo  (drops only x_lo*w_lo ~2e-7 — zero
// SFN flips; R13/R16 proved the 2-pass shortcut fails at 5.86e-3).
//   steps 0..31:  stage {A_hi, A_lo, B_h} (24KB/buf) -> 32 MFMA/barrier
//   steps 32..63: stage {A_hi, B_lo}                 -> 16 MFMA/barrier
// LDS 48KB dbuf. Epilogue: Q/K -> RMSNorm+SFN -> bf16 [B,H,L,64];
// V -> SFN -> vT fp16 [B,H,64,L] directly (transpose fused, R13/R14-validated).
__global__ __launch_bounds__(256) void gemm_qkv(
    const u16* __restrict__ a_hi, const u16* __restrict__ a_lo,
    const u16* __restrict__ b_h,  const u16* __restrict__ b_lo,
    const float* __restrict__ bq, const float* __restrict__ bk_,
    const float* __restrict__ bv,
    u16* __restrict__ qb, u16* __restrict__ kb, u16* __restrict__ vt,
    const float* __restrict__ gq, const float* __restrict__ gk)
{
  __shared__ u16 lds[2][12288];   // [0):A_hi [4096):A_lo [8192):B
  const int tid = threadIdx.x;
  const int lane = tid & 63;
  const int w = tid >> 6;
  const int wr = w >> 1, wc = w & 1;
  const int l15 = lane & 15, lq = lane >> 4;
  const int m0 = blockIdx.x * 128;
  const int n0 = blockIdx.y * 128;
  const int K = 1024;

  f32x4 acc[4][4];
  #pragma unroll
  for (int i=0;i<4;i++)
    #pragma unroll
    for (int j=0;j<4;j++) acc[i][j] = (f32x4){0.f,0.f,0.f,0.f};

  auto stage = [&](int buf, int kt){
    u16* base = &lds[buf][0];
    if (kt < 32){
      int kk = kt << 5;
      #pragma unroll
      for (int r=0;r<2;r++){
        const u16* g = a_hi + (size_t)(m0 + (tid>>2) + r*64)*K + kk + (tid&3)*8;
        gld_lds16(g, base + w*512 + r*2048);
      }
      #pragma unroll
      for (int r=0;r<2;r++){
        const u16* g = a_lo + (size_t)(m0 + (tid>>2) + r*64)*K + kk + (tid&3)*8;
        gld_lds16(g, base + 4096 + w*512 + r*2048);
      }
      #pragma unroll
      for (int r=0;r<2;r++){
        const u16* g = b_h + (size_t)(n0 + (tid>>2) + r*64)*K + kk + (tid&3)*8;
        gld_lds16(g, base + 8192 + w*512 + r*2048);
      }
    } else {
      int kk = (kt-32) << 5;
      #pragma unroll
      for (int r=0;r<2;r++){
        const u16* g = a_hi + (size_t)(m0 + (tid>>2) + r*64)*K + kk + (tid&3)*8;
        gld_lds16(g, base + w*512 + r*2048);
      }
      #pragma unroll
      for (int r=0;r<2;r++){
        const u16* g = b_lo + (size_t)(n0 + (tid>>2) + r*64)*K + kk + (tid&3)*8;
        gld_lds16(g, base + 8192 + w*512 + r*2048);
      }
    }
  };

  const int koff = lq*8;
  const int rowa = wr*64 + l15;
  const int rowb = wc*64 + l15;

  stage(0, 0);
  for (int kt=0; kt<64; ++kt){
    __syncthreads();
    if (kt+1 < 64) stage((kt+1)&1, kt+1);
    const u16* la = &lds[kt&1][0];
    const u16* lb = &lds[kt&1][8192];
    f16x8 bfv[4];
    #pragma unroll
    for (int j=0;j<4;j++) bfv[j] = *(const f16x8*)&lb[(rowb + j*16)*32 + koff];
    f16x8 af[4];
    #pragma unroll
    for (int i=0;i<4;i++) af[i] = *(const f16x8*)&la[(rowa + i*16)*32 + koff];
    #pragma unroll
    for (int i=0;i<4;i++)
      #pragma unroll
      for (int j=0;j<4;j++)
        acc[i][j] = mfma_f16(af[i], bfv[j], acc[i][j]);
    if (kt < 32){
      const u16* ll = &lds[kt&1][4096];
      f16x8 al[4];
      #pragma unroll
      for (int i=0;i<4;i++) al[i] = *(const f16x8*)&ll[(rowa + i*16)*32 + koff];
      #pragma unroll
      for (int i=0;i<4;i++)
        #pragma unroll
        for (int j=0;j<4;j++)
          acc[i][j] = mfma_f16(al[i], bfv[j], acc[i][j]);
    }
  }

  const int gcolbase = n0 + wc*64;
  const int sidx = gcolbase >> 6;   // 0..47 head-segment
  const int ttype = sidx < 16 ? 0 : (sidx < 32 ? 1 : 2);

  if (ttype < 2){
    // ---- Q/K: bias -> RMSNorm(g) -> SFN -> qb/kb [B,H,L,64] bf16 (exact) ----
    u16* dst = ttype==0 ? qb : kb;
    const float* bsrc = ttype==0 ? bq : bk_;
    const int h = sidx - (ttype==1 ? 16 : 0);
    float gvals[4], bvals[4];
    #pragma unroll
    for (int j=0;j<4;j++){
      int dh = j*16 + l15;
      bvals[j] = bsrc[(gcolbase & 1023) + dh];
      gvals[j] = ttype==0 ? gq[dh] : gk[dh];
    }
    #pragma unroll
    for (int i=0;i<4;i++){
      #pragma unroll
      for (int r=0;r<4;r++){
        float tv[4];
        float ssq = 0.f;
        #pragma unroll
        for (int j=0;j<4;j++){ tv[j] = acc[i][j][r] + bvals[j]; ssq += tv[j]*tv[j]; }
        ssq += __shfl_xor(ssq, 1);
        ssq += __shfl_xor(ssq, 2);
        ssq += __shfl_xor(ssq, 4);
        ssq += __shfl_xor(ssq, 8);
        float s = 1.0f / sqrtf(ssq * (1.0f/64.0f) + 1e-6f);
        int row = m0 + wr*64 + i*16 + lq*4 + r;
        int bi = row >> 11, li = row & 2047;
        size_t obase = ((size_t)(bi*NHEAD + h)*SEQ + li)*HEAD_DIM;
        #pragma unroll
        for (int j=0;j<4;j++){
          float val = tv[j] * s * gvals[j];
          float z = rintf(val * 2.0f);           // round-half-even == jnp.round
          z = fminf(8.0f, fmaxf(-8.0f, z));
          dst[obase + j*16 + l15] = f2bf(z * 0.5f);   // exact in bf16
        }
      }
    }
  } else {
    // ---- V: bias -> SFN -> vT fp16 [B,H,64,L] directly (transpose fused) ----
    const int h = sidx - 32;
    float bvals[4];
    #pragma unroll
    for (int j=0;j<4;j++) bvals[j] = bv[(gcolbase - 2048) + j*16 + l15];
    #pragma unroll
    for (int i=0;i<4;i++){
      int row0 = m0 + wr*64 + i*16 + lq*4;   // 4 consecutive rows
      int bi = row0 >> 11, li0 = row0 & 2047;
      #pragma unroll
      for (int j=0;j<4;j++){
        u16 h4[4];
        #pragma unroll
        for (int r=0;r<4;r++){
          float val = acc[i][j][r] + bvals[j];
          float z = rintf(val * 2.0f);
          z = fminf(8.0f, fmaxf(-8.0f, z));
          h4[r] = f2h(z * 0.5f);               // exact in fp16
        }
        int dh = j*16 + l15;
        *(ushort4*)&vt[(((size_t)(bi*NHEAD + h))*HEAD_DIM + dh)*SEQ + li0] =
            make_ushort4(h4[0],h4[1],h4[2],h4[3]);
      }
    }
  }
}

// ---------------- GEMM: out = attn * wo^T + bias (fp16 operands, fp32 out) ---
__global__ __launch_bounds__(256) void gemm_bt(
    const u16* __restrict__ a_h, const u16* __restrict__ b_h,
    const float* __restrict__ bias, float* __restrict__ out_f,
    int M, int N, int K)
{
  __shared__ u16 lds[2][8192];
  const int tid = threadIdx.x;
  const int lane = tid & 63;
  const int w = tid >> 6;
  const int wr = w >> 1, wc = w & 1;
  const int m0 = blockIdx.x * 128;
  const int n0 = blockIdx.y * 128;
  const int NT = K / 32;

  f32x4 acc[4][4];
  #pragma unroll
  for (int i=0;i<4;i++)
    #pragma unroll
    for (int j=0;j<4;j++) acc[i][j] = (f32x4){0.f,0.f,0.f,0.f};

  auto stage = [&](int buf, int kt){
    int kk = kt * 32;
    u16* base = &lds[buf][0];
    #pragma unroll
    for (int r=0;r<2;r++){
      const u16* g = a_h + (size_t)(m0 + (tid>>2) + r*64)*K + kk + (tid&3)*8;
      gld_lds16(g, base + w*512 + r*2048);
    }
    #pragma unroll
    for (int r=0;r<2;r++){
      const u16* g = b_h + (size_t)(n0 + (tid>>2) + r*64)*K + kk + (tid&3)*8;
      gld_lds16(g, base + 4096 + w*512 + r*2048);
    }
  };

  stage(0, 0);
  for (int kt=0; kt<NT; ++kt){
    __syncthreads();
    if (kt+1 < NT) stage((kt+1)&1, kt+1);
    const u16* la = &lds[kt&1][0];
    const u16* lb = &lds[kt&1][4096];
    const int koff = (lane>>4)*8;
    const int rowa = wr*64 + (lane&15);
    const int rowb = wc*64 + (lane&15);
    f16x8 af[4], bfv[4];
    #pragma unroll
    for (int i=0;i<4;i++) af[i]  = *(const f16x8*)&la[(rowa + i*16)*32 + koff];
    #pragma unroll
    for (int i=0;i<4;i++) bfv[i] = *(const f16x8*)&lb[(rowb + i*16)*32 + koff];
    #pragma unroll
    for (int i=0;i<4;i++)
      #pragma unroll
      for (int j=0;j<4;j++)
        acc[i][j] = mfma_f16(af[i], bfv[j], acc[i][j]);
  }

  const int gcolbase = n0 + wc*64;
  #pragma unroll
  for (int j=0;j<4;j++){
    float bj = bias[gcolbase + j*16 + (lane&15)];
    #pragma unroll
    for (int i=0;i<4;i++){
      int row = m0 + wr*64 + i*16 + (lane>>4)*4;
      #pragma unroll
      for (int r=0;r<4;r++)
        out_f[(size_t)(row+r)*N + gcolbase + j*16 + (lane&15)] = acc[i][j][r] + bj;
    }
  }
}

// ---------------- flash attention (v8: fp16 P, shift-by-4 via C-init) -------
// Scores bounded |s|<=12.5; QK accumulator INITIALIZED to -4 (free shift):
// P' = exp(s-4) <= e^8.5 = 4.9e3 < fp16 max; shift cancels exactly in o/l.
// P stored fp16 (2^-11 rel vs bf16's 2^-8 -> floor drops ~4-8x). V fp16 (exact).
__global__ __launch_bounds__(256) void attn_kernel(
    const u16* __restrict__ qb, const u16* __restrict__ kb, const u16* __restrict__ vt,
    u16* __restrict__ attn_out)
{
  __shared__ u16 lds_k[2][KVBLK*64];   // [kv][d] bf16, swizzled (16KB each)
  __shared__ u16 lds_v[2][64*KVBLK];   // [dh][kv] fp16, swizzled (16KB each)
  const int tid = threadIdx.x, lane = tid & 63, w = tid >> 6;
  const int bh = blockIdx.y;
  const int q0 = blockIdx.x * 128;
  const size_t kvbase = (size_t)bh * SEQ * HEAD_DIM;
  const size_t vtbase = (size_t)bh * HEAD_DIM * SEQ;
  const int l31 = lane & 31, hi = lane >> 5;

  // Q frags (B operand): Q[q0+w*32+l31][kd*16 + hi*8 + j], scale 0.125 exact
  bf16x8 qf[4];
  #pragma unroll
  for (int kd=0; kd<4; kd++){
    const u16* g = qb + kvbase + (size_t)(q0 + w*32 + l31)*64 + kd*16 + hi*8;
    bf16x8 v = *(const bf16x8*)g;
    #pragma unroll
    for (int j=0;j<8;j++) ((u16*)&v)[j] = f2bf(bf2f((u16)v[j]) * 0.125f);
    qf[kd] = v;
  }

  float l_s = 0.f;
  f32x16 o0, o1;
  #pragma unroll
  for (int r=0;r<16;r++){ o0[r] = 0.f; o1[r] = 0.f; }

  auto stage = [&](int buf, int t){
    const int kv0 = t * KVBLK;
    #pragma unroll
    for (int r=0;r<4;r++){
      int idx = tid + r*256;
      int row = idx >> 3, grp = idx & 7;          // K: [128 kv][8 grp]
      const u16* g = kb + kvbase + (size_t)(kv0 + row)*64 + ((grp ^ swz8(row))<<3);
      gld_lds16(g, &lds_k[buf][idx<<3]);
    }
    #pragma unroll
    for (int r=0;r<4;r++){
      int idx = tid + r*256;
      int row = idx >> 4, grp = idx & 15;         // V: [64 dh][16 grp]
      const u16* g = vt + vtbase + (size_t)row*SEQ + kv0 + ((grp ^ swz8(row))<<3);
      gld_lds16(g, &lds_v[buf][idx<<3]);
    }
  };

  stage(0, 0);
  for (int t=0; t<KVTILES; ++t){
    __syncthreads();                        // tile t staged; buf t^1 free
    if (t+1 < KVTILES) stage((t+1)&1, t+1); // overlap with compute(t)
    const int buf = t & 1;

    #pragma unroll
    for (int half=0; half<2; ++half){
      // ---- S^T = K Q − 4 (shift folded into accumulator init) ----
      f32x16 s0, s1;
      #pragma unroll
      for (int r=0;r<16;r++){ s0[r] = -4.f; s1[r] = -4.f; }
      const int row0 = half*64 + l31;
      const int row1 = half*64 + 32 + l31;
      __builtin_amdgcn_s_setprio(1);
      #pragma unroll
      for (int kd=0; kd<4; kd++){
        bf16x8 a0 = *(const bf16x8*)&lds_k[buf][row0*64 + (((kd*2+hi) ^ swz8(row0))<<3)];
        bf16x8 a1 = *(const bf16x8*)&lds_k[buf][row1*64 + (((kd*2+hi) ^ swz8(row1))<<3)];
        s0 = mfma32_bf16(a0, qf[kd], s0);
        s1 = mfma32_bf16(a1, qf[kd], s1);
      }
      __builtin_amdgcn_s_setprio(0);

      // ---- P' = exp(s−4) (bounded; no max-tracking) ----
      float rsum = 0.f;
      #pragma unroll
      for (int r=0;r<16;r++){ float p = __expf(s0[r]); s0[r] = p; rsum += p; }
      #pragma unroll
      for (int r=0;r<16;r++){ float p = __expf(s1[r]); s1[r] = p; rsum += p; }
      rsum += __shfl_xor(rsum, 32);
      l_s += rsum;

      // ---- P -> fp16 packed words (cvt_pkrtz: 1 instr / 2 vals) ----
      uint32_t W[2][4][2];
      #pragma unroll
      for (int g=0; g<4; g++){
        W[0][g][0] = pack_h2(s0[g*4+0], s0[g*4+1]);
        W[0][g][1] = pack_h2(s0[g*4+2], s0[g*4+3]);
        W[1][g][0] = pack_h2(s1[g*4+0], s1[g*4+1]);
        W[1][g][1] = pack_h2(s1[g*4+2], s1[g*4+3]);
      }
      // ---- assemble PV A-frags in-register (T12) ----
      f16x8 pa[4];
      #pragma unroll
      for (int ks=0; ks<4; ks++){
        const int kvb = ks >> 1, ks0 = ks & 1;
        uint32_t own0 = hi ? W[kvb][ks0*2+1][0] : W[kvb][ks0*2][0];
        uint32_t own1 = hi ? W[kvb][ks0*2+1][1] : W[kvb][ks0*2][1];
        uint32_t t0   = hi ? W[kvb][ks0*2][0]   : W[kvb][ks0*2+1][0];
        uint32_t t1   = hi ? W[kvb][ks0*2][1]   : W[kvb][ks0*2+1][1];
        uint32_t sw0  = (uint32_t)__shfl_xor((int)t0, 32);
        uint32_t sw1  = (uint32_t)__shfl_xor((int)t1, 32);
        uint32_t words[4];
        words[0] = hi ? sw0 : own0;
        words[1] = hi ? sw1 : own1;
        words[2] = hi ? own0 : sw0;
        words[3] = hi ? own1 : sw1;
        pa[ks] = *(const f16x8*)words;
      }

      // ---- O += P V (fp16 MFMA) ----
      __builtin_amdgcn_s_setprio(1);
      #pragma unroll
      for (int ks=0; ks<4; ks++){
        const int rv0 = l31, rv1 = 32 + l31;
        const int cg = half*8 + ks*2 + hi;
        f16x8 vb0 = *(const f16x8*)&lds_v[buf][rv0*KVBLK + ((cg ^ swz8(rv0))<<3)];
        f16x8 vb1 = *(const f16x8*)&lds_v[buf][rv1*KVBLK + ((cg ^ swz8(rv1))<<3)];
        o0 = mfma32_f16(pa[ks], vb0, o0);
        o1 = mfma32_f16(pa[ks], vb1, o1);
      }
      __builtin_amdgcn_s_setprio(0);
    }
  }

  // ---- epilogue: fp16 output ----
  const int b = bh >> 4, h = bh & 15;
  #pragma unroll
  for (int r=0;r<16;r++){
    int q = (r&3) + 8*(r>>2) + 4*hi;
    float linv = 1.0f / __shfl(l_s, q);
    int row = q0 + w*32 + q;
    size_t obase = ((size_t)b*SEQ + row)*D_MODEL + h*64;
    attn_out[obase + l31]      = f2h(o0[r] * linv);
    attn_out[obase + 32 + l31] = f2h(o1[r] * linv);
  }
}

// ---------------- host ----------------
extern "C" void kernel_launch(void* const* d_in, const int* in_sizes, int n_in,
                              void* d_out, int out_size, void* d_ws, size_t ws_size,
                              hipStream_t stream){
  const float* x  = (const float*)d_in[0];
  const float* wq = (const float*)d_in[1];
  const float* bq = (const float*)d_in[2];
  const float* wk = (const float*)d_in[3];
  const float* bk = (const float*)d_in[4];
  const float* wv = (const float*)d_in[5];
  const float* bv = (const float*)d_in[6];
  const float* wo = (const float*)d_in[7];
  const float* bo = (const float*)d_in[8];
  const float* gq = (const float*)d_in[9];
  const float* gk = (const float*)d_in[10];
  float* out = (float*)d_out;

  char* ws = (char*)d_ws;
  size_t off = 0;
  auto alloc = [&](size_t bytes) -> char* {
    char* p = ws + off; off += (bytes + 255) & ~(size_t)255; return p;
  };
  const size_t ND = (size_t)MROWS * D_MODEL;       // 4M
  u16* x_hi    = (u16*)alloc(ND*2);                // fp16
  u16* x_lo    = (u16*)alloc(ND*2);                // fp16
  u16* wqkv_h  = (u16*)alloc((size_t)3072*1024*2); // fp16 (wq|wk|wv hi)
  u16* wqkv_lo = (u16*)alloc((size_t)3072*1024*2); // fp16 (wq|wk|wv lo)
  u16* wo_h    = (u16*)alloc((size_t)1024*1024*2); // fp16
  u16* q_bf    = (u16*)alloc(ND*2);
  u16* k_bf    = (u16*)alloc(ND*2);
  u16* vT      = (u16*)alloc(ND*2);                // fp16
  u16* attn_h  = (u16*)alloc(ND*2);                // fp16
  (void)ws_size; (void)in_sizes; (void)n_in; (void)out_size;

  pack_all<<<8192, 256, 0, stream>>>(x, wq, wk, wv, wo,
        x_hi, x_lo, wqkv_h, wqkv_lo, wo_h);

  gemm_qkv<<<dim3(32,24), 256, 0, stream>>>(x_hi, x_lo, wqkv_h, wqkv_lo,
        bq, bk, bv, q_bf, k_bf, vT, gq, gk);

  attn_kernel<<<dim3(16,32), 256, 0, stream>>>(q_bf, k_bf, vT, attn_h);

  gemm_bt<<<dim3(32,8), 256, 0, stream>>>(attn_h, wo_h, bo, out, MROWS, 1024, 1024);
}